// Round 4
// baseline (855.792 us; speedup 1.0000x reference)
//
#include <hip/hip_runtime.h>
#include <math.h>

#define NNODES 100000
#define NEDGES 1600000
#define FEAT 256
#define HID 128
#define NCLS 64
#define RPB 512                 // rows per bucket
#define NBG 196                 // buckets per graph = ceil(100000/512)
#define NB3 (3 * NBG)           // 588
#define CAP 8832                // per-bucket edge capacity (mean 8192 + 7 sigma)
#define SC_CHUNK 8192           // edges per scatter block (LDS-staged)
#define SC_THREADS 1024         // 16 waves/block
#define GRP 16                  // rows per MFMA spmm wave-group
#define NGRP (NNODES / GRP)     // 6250 (exact)
#define SLOTP 33                // padded slot dim (words) -> conflict-free staging

typedef __attribute__((ext_vector_type(8))) short bf16x8;
typedef __attribute__((ext_vector_type(4))) float f32x4;
typedef __attribute__((ext_vector_type(2))) float f32x2;

__device__ __forceinline__ float bf2f(unsigned int u16) {
  union { unsigned int i; float f; } c; c.i = u16 << 16; return c.f;
}
__device__ __forceinline__ unsigned short f2bf(float f) {
  union { float f; unsigned int i; } c; c.f = f;
  unsigned int u = c.i;
  return (unsigned short)((u + 0x7fffu + ((u >> 16) & 1u)) >> 16);  // RNE
}

// 8 bf16 (as uint4) * scalar-pair vv -> 4 packed f32x2 accumulators
__device__ __forceinline__ void fma8(const uint4 u, const f32x2 vv, f32x2* a) {
  f32x2 p0, p1, p2, p3;
  p0.x = __uint_as_float(u.x << 16); p0.y = __uint_as_float(u.x & 0xffff0000u);
  p1.x = __uint_as_float(u.y << 16); p1.y = __uint_as_float(u.y & 0xffff0000u);
  p2.x = __uint_as_float(u.z << 16); p2.y = __uint_as_float(u.z & 0xffff0000u);
  p3.x = __uint_as_float(u.w << 16); p3.y = __uint_as_float(u.w & 0xffff0000u);
  a[0] += p0 * vv; a[1] += p1 * vv; a[2] += p2 * vv; a[3] += p3 * vv;
}

// ---------------- bucket histogram: bhist[g*NBG + (row>>9)] ----------------
__global__ __launch_bounds__(256) void k_bhist(const int* __restrict__ r0,
                                               const int* __restrict__ r1,
                                               const int* __restrict__ r2,
                                               int* __restrict__ bhist) {
  __shared__ int h[NBG];
  int g = blockIdx.y;
  const int* rr = (g == 0) ? r0 : (g == 1 ? r1 : r2);
  int tid = threadIdx.x;
  for (int i = tid; i < NBG; i += 256) h[i] = 0;
  __syncthreads();
  int base = blockIdx.x * 4096;
#pragma unroll
  for (int k = 0; k < 16; k++) {
    int e = base + k * 256 + tid;
    if (e < NEDGES) atomicAdd(&h[rr[e] >> 9], 1);
  }
  __syncthreads();
  for (int i = tid; i < NBG; i += 256)
    if (h[i]) atomicAdd(&bhist[g * NBG + i], h[i]);
}

// single-block exclusive scan over NB3 bucket counts -> boff[0..NB3]
__global__ __launch_bounds__(1024) void k_bscan(const int* __restrict__ bhist,
                                                int* __restrict__ boff) {
  __shared__ int sd[2][1024];
  int tid = threadIdx.x;
  int v = (tid < NB3) ? bhist[tid] : 0;
  sd[0][tid] = v;
  __syncthreads();
  int cur = 0;
  for (int off = 1; off < 1024; off <<= 1) {
    int nv = sd[cur][tid];
    if (tid >= off) nv += sd[cur][tid - off];
    sd[cur ^ 1][tid] = nv;
    __syncthreads();
    cur ^= 1;
  }
  int incl = sd[cur][tid];
  if (tid < NB3) boff[tid] = incl - v;
  if (tid == NB3 - 1) boff[NB3] = incl;
}

// ---------------- pass A: coarse bucket scatter (LDS-staged, coalesced writes) ---
__global__ __launch_bounds__(SC_THREADS) void k_bucket_scatter(
    const int* __restrict__ r0, const int* __restrict__ r1, const int* __restrict__ r2,
    const int* __restrict__ c0, const int* __restrict__ c1, const int* __restrict__ c2,
    const float* __restrict__ v0, const float* __restrict__ v1, const float* __restrict__ v2,
    int* __restrict__ gcur, int2* __restrict__ edges) {
  __shared__ int2 stage[SC_CHUNK];            // 64 KB
  __shared__ unsigned char bid[SC_CHUNK];     // 8 KB  (NBG=196 < 256)
  __shared__ int hist[NBG];
  __shared__ int lbase[NBG];
  __shared__ int gstart[NBG];
  __shared__ int cur[NBG];
  __shared__ int sd[2][256];
  int g = blockIdx.y;
  const int*   rr = (g == 0) ? r0 : (g == 1 ? r1 : r2);
  const int*   cc = (g == 0) ? c0 : (g == 1 ? c1 : c2);
  const float* vv = (g == 0) ? v0 : (g == 1 ? v1 : v2);
  int tid = threadIdx.x;
  int base = blockIdx.x * SC_CHUNK;
  int cnt_blk = NEDGES - base;
  if (cnt_blk > SC_CHUNK) cnt_blk = SC_CHUNK;

  for (int i = tid; i < NBG; i += SC_THREADS) hist[i] = 0;
  __syncthreads();

  int rowv[SC_CHUNK / SC_THREADS];
  int colv[SC_CHUNK / SC_THREADS];
  float valv[SC_CHUNK / SC_THREADS];
#pragma unroll
  for (int k = 0; k < SC_CHUNK / SC_THREADS; k++) {
    int e = base + k * SC_THREADS + tid;
    bool ok = e < NEDGES;
    rowv[k] = ok ? rr[e] : -1;
    colv[k] = ok ? cc[e] : 0;
    valv[k] = ok ? vv[e] : 0.f;
    if (ok) atomicAdd(&hist[rowv[k] >> 9], 1);
  }
  __syncthreads();

  if (tid < 256) sd[0][tid] = (tid < NBG) ? hist[tid] : 0;
  __syncthreads();
  int c = 0;
  for (int off = 1; off < 256; off <<= 1) {
    if (tid < 256) {
      int nv = sd[c][tid];
      if (tid >= off) nv += sd[c][tid - off];
      sd[c ^ 1][tid] = nv;
    }
    __syncthreads();
    c ^= 1;
  }
  if (tid < NBG) {
    int cn = hist[tid];
    int excl = sd[c][tid] - cn;
    lbase[tid] = excl;
    cur[tid] = excl;
    gstart[tid] = cn ? atomicAdd(&gcur[g * NBG + tid], cn) : 0;
  }
  __syncthreads();

#pragma unroll
  for (int k = 0; k < SC_CHUNK / SC_THREADS; k++) {
    if (rowv[k] >= 0) {
      int b = rowv[k] >> 9;
      int p = atomicAdd(&cur[b], 1);
      stage[p] = make_int2(((rowv[k] & (RPB - 1)) << 17) | colv[k], __float_as_int(valv[k]));
      bid[p] = (unsigned char)b;
    }
  }
  __syncthreads();

  for (int i = tid; i < cnt_blk; i += SC_THREADS) {
    int b = bid[i];
    int dst = gstart[b] + (i - lbase[b]);
    edges[dst] = stage[i];
  }
}

// ---------------- pass B: in-bucket counting sort (LDS scatter, coalesced IO) ---
__global__ __launch_bounds__(512) void k_bucket_sort(const int* __restrict__ boff,
                                                     int2* __restrict__ edges,
                                                     int* __restrict__ row_ptr_all) {
  __shared__ int2 stage[CAP];   // 70.7 KB
  __shared__ int hist[RPB];
  __shared__ int sd[2][RPB];
  __shared__ int cur[RPB];
  int g = blockIdx.y, b = blockIdx.x;
  int tid = threadIdx.x;
  int idx = g * NBG + b;
  int base = boff[idx];
  int count = boff[idx + 1] - base;
  if (count > CAP) count = CAP;
  hist[tid] = 0;
  __syncthreads();

  const int KSL = (CAP + 511) / 512;   // 18 slots/thread
  int2 ev[KSL];
#pragma unroll
  for (int k = 0; k < KSL; k++) {
    int i = tid + k * 512;
    if (i < count) {
      ev[k] = edges[base + i];
      atomicAdd(&hist[ev[k].x >> 17], 1);
    }
  }
  __syncthreads();

  int v = hist[tid];
  sd[0][tid] = v;
  __syncthreads();
  int c2 = 0;
  for (int off = 1; off < 512; off <<= 1) {
    int nv = sd[c2][tid];
    if (tid >= off) nv += sd[c2][tid - off];
    sd[c2 ^ 1][tid] = nv;
    __syncthreads();
    c2 ^= 1;
  }
  int excl = sd[c2][tid] - v;
  int row = b * RPB + tid;
  if (row <= NNODES) row_ptr_all[g * (NNODES + 1) + row] = base + excl;
  cur[tid] = excl;
  __syncthreads();

#pragma unroll
  for (int k = 0; k < KSL; k++) {
    int i = tid + k * 512;
    if (i < count) {
      int lr = ev[k].x >> 17;
      int p = atomicAdd(&cur[lr], 1);
      // keep 4-bit row-in-group in bits 17-20 for the MFMA spmm A-matching
      stage[p] = make_int2(((lr & 15) << 17) | (ev[k].x & 0x1FFFF), ev[k].y);
    }
  }
  __syncthreads();

  for (int i = tid; i < count; i += 512) edges[base + i] = stage[i];
}

// ---------------- prep ----------------
__global__ __launch_bounds__(256) void k_convert_bf16(const float* __restrict__ src,
                                                      unsigned short* __restrict__ dst,
                                                      int n4) {
  int i = blockIdx.x * blockDim.x + threadIdx.x;
  if (i < n4) {
    float4 v = ((const float4*)src)[i];
    ushort4 o;
    o.x = f2bf(v.x); o.y = f2bf(v.y); o.z = f2bf(v.z); o.w = f2bf(v.w);
    ((ushort4*)dst)[i] = o;
  }
}

__global__ __launch_bounds__(256) void k_transpose3(const float* __restrict__ s0,
                                                    const float* __restrict__ s1,
                                                    const float* __restrict__ s2,
                                                    unsigned short* __restrict__ d0,
                                                    unsigned short* __restrict__ d1,
                                                    unsigned short* __restrict__ d2,
                                                    int K, int N) {
  int g = blockIdx.y;
  const float* src = (g == 0) ? s0 : (g == 1 ? s1 : s2);
  unsigned short* dst = (g == 0) ? d0 : (g == 1 ? d1 : d2);
  int idx = blockIdx.x * 256 + threadIdx.x;
  if (idx < K * N) {
    int k = idx / N, n = idx % N;
    dst[(size_t)n * K + k] = f2bf(src[idx]);
  }
}

// ---------------- batched bf16 MFMA GEMMs ----------------
__global__ __launch_bounds__(256) void k_gemm1_b(const unsigned short* __restrict__ A,
                                                 const unsigned short* __restrict__ WtA,
                                                 unsigned short* __restrict__ C3, int M) {
  int bxy = blockIdx.x;
  int g = bxy % 3;
  int bx = bxy / 3;
  const unsigned short* Wt = WtA + (size_t)g * HID * FEAT;
  unsigned short* C = C3 + (size_t)g * M * HID;
  int tid = threadIdx.x;
  int wave = tid >> 6, lane = tid & 63;
  int quad = lane >> 4, r = lane & 15;
  int m0 = bx * 128 + wave * 32;
  int ra0 = m0 + r;      if (ra0 >= M) ra0 = 0;
  int ra1 = m0 + 16 + r; if (ra1 >= M) ra1 = 0;
  const unsigned short* pa0 = A + (size_t)ra0 * FEAT + quad * 8;
  const unsigned short* pa1 = A + (size_t)ra1 * FEAT + quad * 8;
  f32x4 acc[2][8];
#pragma unroll
  for (int i = 0; i < 2; i++)
#pragma unroll
    for (int j = 0; j < 8; j++) acc[i][j] = (f32x4){0.f, 0.f, 0.f, 0.f};
  for (int k0 = 0; k0 < FEAT; k0 += 32) {
    bf16x8 a0 = *(const bf16x8*)(pa0 + k0);
    bf16x8 a1 = *(const bf16x8*)(pa1 + k0);
#pragma unroll
    for (int nt = 0; nt < 8; nt++) {
      bf16x8 b = *(const bf16x8*)(Wt + (size_t)(nt * 16 + r) * FEAT + k0 + quad * 8);
      acc[0][nt] = __builtin_amdgcn_mfma_f32_16x16x32_bf16(a0, b, acc[0][nt], 0, 0, 0);
      acc[1][nt] = __builtin_amdgcn_mfma_f32_16x16x32_bf16(a1, b, acc[1][nt], 0, 0, 0);
    }
  }
#pragma unroll
  for (int t = 0; t < 2; t++)
#pragma unroll
    for (int reg = 0; reg < 4; reg++) {
      int row = m0 + t * 16 + quad * 4 + reg;
      if (row < M) {
#pragma unroll
        for (int nt = 0; nt < 8; nt++)
          C[(size_t)row * HID + nt * 16 + r] = f2bf(acc[t][nt][reg]);
      }
    }
}

__global__ __launch_bounds__(256) void k_gemm2_b(const unsigned short* __restrict__ A3,
                                                 const unsigned short* __restrict__ WtA,
                                                 unsigned short* __restrict__ C3, int M) {
  int g = blockIdx.y;
  const unsigned short* A = A3 + (size_t)g * M * HID;
  const unsigned short* Wt = WtA + (size_t)g * NCLS * HID;
  unsigned short* C = C3 + (size_t)g * M * NCLS;
  int tid = threadIdx.x;
  int wave = tid >> 6, lane = tid & 63;
  int quad = lane >> 4, r = lane & 15;
  int m0 = blockIdx.x * 128 + wave * 32;
  int ra0 = m0 + r;      if (ra0 >= M) ra0 = 0;
  int ra1 = m0 + 16 + r; if (ra1 >= M) ra1 = 0;
  const unsigned short* pa0 = A + (size_t)ra0 * HID + quad * 8;
  const unsigned short* pa1 = A + (size_t)ra1 * HID + quad * 8;
  f32x4 acc[2][4];
#pragma unroll
  for (int i = 0; i < 2; i++)
#pragma unroll
    for (int j = 0; j < 4; j++) acc[i][j] = (f32x4){0.f, 0.f, 0.f, 0.f};
  for (int k0 = 0; k0 < HID; k0 += 32) {
    bf16x8 a0 = *(const bf16x8*)(pa0 + k0);
    bf16x8 a1 = *(const bf16x8*)(pa1 + k0);
#pragma unroll
    for (int nt = 0; nt < 4; nt++) {
      bf16x8 b = *(const bf16x8*)(Wt + (size_t)(nt * 16 + r) * HID + k0 + quad * 8);
      acc[0][nt] = __builtin_amdgcn_mfma_f32_16x16x32_bf16(a0, b, acc[0][nt], 0, 0, 0);
      acc[1][nt] = __builtin_amdgcn_mfma_f32_16x16x32_bf16(a1, b, acc[1][nt], 0, 0, 0);
    }
  }
#pragma unroll
  for (int t = 0; t < 2; t++)
#pragma unroll
    for (int reg = 0; reg < 4; reg++) {
      int row = m0 + t * 16 + quad * 4 + reg;
      if (row < M) {
#pragma unroll
        for (int nt = 0; nt < 4; nt++)
          C[(size_t)row * NCLS + nt * 16 + r] = f2bf(acc[t][nt][reg]);
      }
    }
}

// ---------------- MFMA SpMM (HID=128): one wave per 16-row group ----------------
// A[m][k] = val(slot k) if slot k belongs to group-row m (register-built, f2bf).
// B[k][n]: gathered dense rows staged in LDS as interleaved feat-pair entries:
//   word[fp][slot] at index fp*SLOTP + slot holds {feat 2fp (lo16), feat 2fp+1 (hi16)}.
// Staging = gathered uint4 dwords written verbatim (bank (4n+j+4it+q)%32: 2-way, free).
// B-fragment = adjacent word pairs (pair-lanes broadcast) + v_perm half-select.
// No exotic instructions: layouts verified against the proven k_gemm1 operand maps.
__global__ __launch_bounds__(256) void k_spmm128_mfma(const int* __restrict__ rp_all,
                                                      const int2* __restrict__ edges,
                                                      const unsigned short* __restrict__ dense3,
                                                      unsigned short* __restrict__ out3) {
  __shared__ unsigned int Lw_all[4][64 * SLOTP];   // 8448 B per wave, 33 KB/block
  int g = blockIdx.y;
  const int* rp = rp_all + (size_t)g * (NNODES + 1);
  const unsigned short* dense = dense3 + (size_t)g * NNODES * HID;
  unsigned short* out = out3 + (size_t)g * NNODES * HID;
  int tid = threadIdx.x;
  int wave = tid >> 6, lane = tid & 63;
  int q = lane >> 4, n = lane & 15;
  int grp_id = blockIdx.x * 4 + wave;
  if (grp_id >= NGRP) return;
  int r0 = grp_id * GRP;
  int s = rp[r0], e = rp[r0 + GRP];

  unsigned int* Lw = Lw_all[wave];
  unsigned int* wbase = Lw + (4 * n) * SLOTP + q;          // + it*4, + j*SLOTP
  unsigned int bsel = (n & 1) ? 0x07060302u : 0x05040100u; // v_perm half-select

  f32x4 acc[8];
#pragma unroll
  for (int i = 0; i < 8; i++) acc[i] = (f32x4){0.f, 0.f, 0.f, 0.f};

  for (int kb = 0; kb < e - s; kb += 32) {
    const int2* ep = edges + s + kb;
    // ---- gather 32 dense rows -> interleaved LDS (slack-protected tail reads) ----
#pragma unroll
    for (int it = 0; it < 8; it++) {
      int2 ed = ep[it * 4 + q];
      int col = ed.x & 0x1FFFF;
      col = (col < NNODES) ? col : 0;
      uint4 du = *(const uint4*)(dense + (size_t)col * HID + n * 8);
      unsigned int* wp = wbase + it * 4;
      wp[0] = du.x; wp[SLOTP] = du.y; wp[2 * SLOTP] = du.z; wp[3 * SLOTP] = du.w;
    }
    // ---- build A fragment (vals, row-matched), proven f2bf packing ----
    float fv[8];
#pragma unroll
    for (int p = 0; p < 8; p++) {
      int2 ed = ep[q * 8 + p];
      bool ok = (kb + q * 8 + p) < (e - s);
      bool mt = ((((unsigned)ed.x) >> 17) & 15u) == (unsigned)n;
      fv[p] = (ok && mt) ? __int_as_float(ed.y) : 0.f;
    }
    union { unsigned u[4]; bf16x8 v; } A;
#pragma unroll
    for (int m = 0; m < 4; m++)
      A.u[m] = (unsigned)f2bf(fv[2 * m]) | ((unsigned)f2bf(fv[2 * m + 1]) << 16);

    // ---- wave-local ordering: staging writes retired before reads ----
    asm volatile("s_waitcnt lgkmcnt(0)" ::: "memory");
    __builtin_amdgcn_sched_barrier(0);

    // ---- B fragments + MFMA: feat f = nt*16+n across slots q*8..q*8+7 ----
#pragma unroll
    for (int nt = 0; nt < 8; nt++) {
      int fp = nt * 8 + (n >> 1);
      const unsigned int* rb = Lw + fp * SLOTP + q * 8;
      union { unsigned u[4]; bf16x8 v; } B;
#pragma unroll
      for (int m = 0; m < 4; m++) {
        unsigned w0 = rb[2 * m];
        unsigned w1 = rb[2 * m + 1];
        B.u[m] = __builtin_amdgcn_perm(w1, w0, bsel);
      }
      acc[nt] = __builtin_amdgcn_mfma_f32_16x16x32_bf16(A.v, B.v, acc[nt], 0, 0, 0);
    }
  }

  // ---- epilogue: relu + direct stores (identical pattern to proven k_gemm1) ----
#pragma unroll
  for (int nt = 0; nt < 8; nt++)
#pragma unroll
    for (int reg = 0; reg < 4; reg++) {
      int row = r0 + q * 4 + reg;
      out[(size_t)row * HID + nt * 16 + n] = f2bf(fmaxf(acc[nt][reg], 0.f));
    }
}

// ---------------- SpMM 64-wide (unchanged passing path) ----------------
__global__ __launch_bounds__(256) void k_spmm64_b(const int* __restrict__ rp_all,
                                                  const int2* __restrict__ edges,
                                                  const unsigned short* __restrict__ dense3,
                                                  const float* __restrict__ b0p,
                                                  const float* __restrict__ b1p,
                                                  const float* __restrict__ b2p,
                                                  const float* __restrict__ gate,
                                                  float* __restrict__ logits3, int n) {
  int g = blockIdx.y;
  const int* rp = rp_all + (size_t)g * (NNODES + 1);
  const unsigned short* dense = dense3 + (size_t)g * NNODES * NCLS;
  const float* bias = (g == 0) ? b0p : (g == 1 ? b1p : b2p);
  float* logits = logits3 + (size_t)g * NNODES * NCLS;
  int w = (blockIdx.x * blockDim.x + threadIdx.x) >> 6;
  int lane = threadIdx.x & 63;
  if (w >= n) return;
  int grp = lane >> 3;    // 0..7
  int sub = lane & 7;     // classes sub*8 .. sub*8+7
  int s = rp[w], e = rp[w + 1];
  f32x2 a0[4], a1[4];
#pragma unroll
  for (int q = 0; q < 4; q++) { a0[q] = (f32x2){0.f, 0.f}; a1[q] = (f32x2){0.f, 0.f}; }
  for (int j = s; j < e; j += 16) {
    int e0 = j + grp, e1 = j + 8 + grp;
    bool k0 = e0 < e, k1 = e1 < e;
    int2 d0 = edges[k0 ? e0 : s];
    int2 d1 = edges[k1 ? e1 : s];
    uint4 u0 = *(const uint4*)(dense + (size_t)(d0.x & 0x1FFFF) * NCLS + sub * 8);
    uint4 u1 = *(const uint4*)(dense + (size_t)(d1.x & 0x1FFFF) * NCLS + sub * 8);
    float f0 = k0 ? __int_as_float(d0.y) : 0.f;
    float f1 = k1 ? __int_as_float(d1.y) : 0.f;
    f32x2 v0; v0.x = f0; v0.y = f0;
    f32x2 v1; v1.x = f1; v1.y = f1;
    fma8(u0, v0, a0);
    fma8(u1, v1, a1);
  }
  float gv = gate[0];
  float scale = (g == 0) ? gv : (1.0f - gv);
  float vc[8];
#pragma unroll
  for (int q = 0; q < 4; q++) {
    float lo = a0[q].x + a1[q].x;
    float hi = a0[q].y + a1[q].y;
    lo += __shfl_xor(lo, 32, 64); lo += __shfl_xor(lo, 16, 64); lo += __shfl_xor(lo, 8, 64);
    hi += __shfl_xor(hi, 32, 64); hi += __shfl_xor(hi, 16, 64); hi += __shfl_xor(hi, 8, 64);
    vc[2 * q] = lo; vc[2 * q + 1] = hi;
  }
  if (grp == 0) {
    float4 b0 = *(const float4*)(bias + sub * 8);
    float4 b1 = *(const float4*)(bias + sub * 8 + 4);
    size_t o = (size_t)w * NCLS + sub * 8;
    *(float4*)(logits + o) = make_float4(scale * (vc[0] + b0.x), scale * (vc[1] + b0.y),
                                         scale * (vc[2] + b0.z), scale * (vc[3] + b0.w));
    *(float4*)(logits + o + 4) = make_float4(scale * (vc[4] + b1.x), scale * (vc[5] + b1.y),
                                             scale * (vc[6] + b1.z), scale * (vc[7] + b1.w));
  }
}

// sum 3 partial logits + fused log_softmax -> final output
__global__ __launch_bounds__(256) void k_final(const float* __restrict__ l3,
                                               float* __restrict__ outp, int n) {
  int t = blockIdx.x * 256 + threadIdx.x;
  int w = t >> 3, sub = t & 7;
  if (w >= n) return;
  size_t o = (size_t)w * NCLS + sub * 8;
  const float* p0 = l3 + o;
  const float* p1 = l3 + (size_t)NNODES * NCLS + o;
  const float* p2 = l3 + (size_t)2 * NNODES * NCLS + o;
  float4 x0 = *(const float4*)p0, x1 = *(const float4*)(p0 + 4);
  float4 y0 = *(const float4*)p1, y1 = *(const float4*)(p1 + 4);
  float4 z0 = *(const float4*)p2, z1 = *(const float4*)(p2 + 4);
  float v[8];
  v[0] = x0.x + y0.x + z0.x; v[1] = x0.y + y0.y + z0.y;
  v[2] = x0.z + y0.z + z0.z; v[3] = x0.w + y0.w + z0.w;
  v[4] = x1.x + y1.x + z1.x; v[5] = x1.y + y1.y + z1.y;
  v[6] = x1.z + y1.z + z1.z; v[7] = x1.w + y1.w + z1.w;
  float m = v[0];
#pragma unroll
  for (int i = 1; i < 8; i++) m = fmaxf(m, v[i]);
  m = fmaxf(m, __shfl_xor(m, 1, 64));
  m = fmaxf(m, __shfl_xor(m, 2, 64));
  m = fmaxf(m, __shfl_xor(m, 4, 64));
  float sum = 0.f;
#pragma unroll
  for (int i = 0; i < 8; i++) sum += expf(v[i] - m);
  sum += __shfl_xor(sum, 1, 64);
  sum += __shfl_xor(sum, 2, 64);
  sum += __shfl_xor(sum, 4, 64);
  float ls = m + logf(sum);
  *(float4*)(outp + o)     = make_float4(v[0] - ls, v[1] - ls, v[2] - ls, v[3] - ls);
  *(float4*)(outp + o + 4) = make_float4(v[4] - ls, v[5] - ls, v[6] - ls, v[7] - ls);
}

extern "C" void kernel_launch(void* const* d_in, const int* in_sizes, int n_in,
                              void* d_out, int out_size, void* d_ws, size_t ws_size,
                              hipStream_t stream) {
  (void)in_sizes; (void)n_in; (void)out_size; (void)ws_size;
  const float* x = (const float*)d_in[0];
  const int*   rows[3]   = {(const int*)d_in[1], (const int*)d_in[4], (const int*)d_in[7]};
  const int*   colsIn[3] = {(const int*)d_in[2], (const int*)d_in[5], (const int*)d_in[8]};
  const float* valsIn[3] = {(const float*)d_in[3], (const float*)d_in[6], (const float*)d_in[9]};
  const float* Whid[3] = {(const float*)d_in[10], (const float*)d_in[13], (const float*)d_in[16]};
  const float* Wout[3] = {(const float*)d_in[11], (const float*)d_in[14], (const float*)d_in[17]};
  const float* bout[3] = {(const float*)d_in[12], (const float*)d_in[15], (const float*)d_in[18]};
  const float* gate = (const float*)d_in[19];
  float* out = (float*)d_out;

  const int N = NNODES, E = NEDGES;
  size_t off = 0;
  auto ws = [&](size_t bytes) {
    void* p = (char*)d_ws + off;
    off += (bytes + 255) & ~(size_t)255;
    return p;
  };
  // Region R1 (76.8 MB): x_bf early; h1[3] / logits3 later (aliased).
  unsigned short* R1 = (unsigned short*)ws((size_t)3 * N * HID * 2);
  unsigned short* x_bf = R1;
  unsigned short* h13  = R1;
  float*          logits3 = (float*)R1;
  unsigned short* hsup3 = (unsigned short*)ws((size_t)3 * N * HID * 2);
  unsigned short* Wt1a = (unsigned short*)ws((size_t)3 * HID * FEAT * 2);
  unsigned short* Wt2a = (unsigned short*)ws((size_t)3 * NCLS * HID * 2);
  int2* edges   = (int2*)ws(((size_t)3 * E + 64) * 8);   // +64 slack for unclamped reads
  int*  rp_all  = (int*) ws((size_t)3 * (N + 1) * 4);
  int*  bhist   = (int*) ws(NB3 * 4);
  int*  boff    = (int*) ws((NB3 + 1) * 4);
  int*  gcur    = (int*) ws(NB3 * 4);

  dim3 b256(256);
  dim3 gRows3((N + 3) / 4, 3);
  int nbGemm = (N + 127) / 128;

  k_convert_bf16<<<(N * FEAT / 4 + 255) / 256, b256, 0, stream>>>(x, x_bf, N * FEAT / 4);
  k_transpose3<<<dim3((FEAT * HID + 255) / 256, 3), b256, 0, stream>>>(
      Whid[0], Whid[1], Whid[2], Wt1a, Wt1a + (size_t)HID * FEAT, Wt1a + (size_t)2 * HID * FEAT,
      FEAT, HID);
  k_transpose3<<<dim3((HID * NCLS + 255) / 256, 3), b256, 0, stream>>>(
      Wout[0], Wout[1], Wout[2], Wt2a, Wt2a + (size_t)NCLS * HID, Wt2a + (size_t)2 * NCLS * HID,
      HID, NCLS);

  hipMemsetAsync(bhist, 0, NB3 * 4, stream);
  k_bhist<<<dim3((E + 4095) / 4096, 3), b256, 0, stream>>>(rows[0], rows[1], rows[2], bhist);
  k_bscan<<<1, 1024, 0, stream>>>(bhist, boff);
  hipMemcpyAsync(gcur, boff, NB3 * 4, hipMemcpyDeviceToDevice, stream);
  k_bucket_scatter<<<dim3((E + SC_CHUNK - 1) / SC_CHUNK, 3), dim3(SC_THREADS), 0, stream>>>(
      rows[0], rows[1], rows[2], colsIn[0], colsIn[1], colsIn[2],
      valsIn[0], valsIn[1], valsIn[2], gcur, edges);
  k_bucket_sort<<<dim3(NBG, 3), 512, 0, stream>>>(boff, edges, rp_all);

  k_gemm1_b<<<dim3(3 * nbGemm), b256, 0, stream>>>(x_bf, Wt1a, hsup3, N);
  k_spmm128_mfma<<<dim3((NGRP + 3) / 4, 3), b256, 0, stream>>>(rp_all, edges, hsup3, h13);
  k_gemm2_b<<<dim3(nbGemm, 3), b256, 0, stream>>>(h13, Wt2a, hsup3, N);
  k_spmm64_b<<<gRows3, b256, 0, stream>>>(rp_all, edges, hsup3, bout[0], bout[1], bout[2],
                                          gate, logits3, N);
  k_final<<<(N * 8 + 255) / 256, b256, 0, stream>>>(logits3, out, N);
}

// Round 5
// 753.020 us; speedup vs baseline: 1.1365x; 1.1365x over previous
//
#include <hip/hip_runtime.h>
#include <math.h>

#define NNODES 100000
#define NEDGES 1600000
#define FEAT 256
#define HID 128
#define NCLS 64
#define RPB 512                 // rows per bucket
#define NBG 196                 // buckets per graph = ceil(100000/512)
#define NB3 (3 * NBG)           // 588
#define CAP 8832                // per-bucket edge capacity (mean 8192 + 7 sigma)
#define SC_CHUNK 8192           // edges per scatter block (LDS-staged)
#define SC_THREADS 1024         // 16 waves/block

typedef __attribute__((ext_vector_type(8))) short bf16x8;
typedef __attribute__((ext_vector_type(4))) float f32x4;
typedef __attribute__((ext_vector_type(2))) float f32x2;

__device__ __forceinline__ float bf2f(unsigned int u16) {
  union { unsigned int i; float f; } c; c.i = u16 << 16; return c.f;
}
__device__ __forceinline__ unsigned short f2bf(float f) {
  union { float f; unsigned int i; } c; c.f = f;
  unsigned int u = c.i;
  return (unsigned short)((u + 0x7fffu + ((u >> 16) & 1u)) >> 16);  // RNE
}

// 8 bf16 (as uint4) * scalar-pair vv -> 4 packed f32x2 accumulators
__device__ __forceinline__ void fma8(const uint4 u, const f32x2 vv, f32x2* a) {
  f32x2 p0, p1, p2, p3;
  p0.x = __uint_as_float(u.x << 16); p0.y = __uint_as_float(u.x & 0xffff0000u);
  p1.x = __uint_as_float(u.y << 16); p1.y = __uint_as_float(u.y & 0xffff0000u);
  p2.x = __uint_as_float(u.z << 16); p2.y = __uint_as_float(u.z & 0xffff0000u);
  p3.x = __uint_as_float(u.w << 16); p3.y = __uint_as_float(u.w & 0xffff0000u);
  a[0] += p0 * vv; a[1] += p1 * vv; a[2] += p2 * vv; a[3] += p3 * vv;
}

// ---------------- pass A: bucket scatter into fixed CAP-slot regions ----------
// No prescan needed: each block reserves per-bucket space with one global
// atomic; bucket b of graph g occupies edges[(g*NBG+b)*CAP ... +CAP).
__global__ __launch_bounds__(SC_THREADS) void k_bucket_scatter(
    const int* __restrict__ r0, const int* __restrict__ r1, const int* __restrict__ r2,
    const int* __restrict__ c0, const int* __restrict__ c1, const int* __restrict__ c2,
    const float* __restrict__ v0, const float* __restrict__ v1, const float* __restrict__ v2,
    int* __restrict__ gcur, int2* __restrict__ edges) {
  __shared__ int2 stage[SC_CHUNK];            // 64 KB
  __shared__ unsigned char bid[SC_CHUNK];     // 8 KB  (NBG=196 < 256)
  __shared__ int hist[NBG];
  __shared__ int lbase[NBG];
  __shared__ int gstart[NBG];
  __shared__ int cur[NBG];
  __shared__ int sd[2][256];
  int g = blockIdx.y;
  const int*   rr = (g == 0) ? r0 : (g == 1 ? r1 : r2);
  const int*   cc = (g == 0) ? c0 : (g == 1 ? c1 : c2);
  const float* vv = (g == 0) ? v0 : (g == 1 ? v1 : v2);
  int tid = threadIdx.x;
  int base = blockIdx.x * SC_CHUNK;
  int cnt_blk = NEDGES - base;
  if (cnt_blk > SC_CHUNK) cnt_blk = SC_CHUNK;

  for (int i = tid; i < NBG; i += SC_THREADS) hist[i] = 0;
  __syncthreads();

  int rowv[SC_CHUNK / SC_THREADS];
  int colv[SC_CHUNK / SC_THREADS];
  float valv[SC_CHUNK / SC_THREADS];
#pragma unroll
  for (int k = 0; k < SC_CHUNK / SC_THREADS; k++) {
    int e = base + k * SC_THREADS + tid;
    bool ok = e < NEDGES;
    rowv[k] = ok ? rr[e] : -1;
    colv[k] = ok ? cc[e] : 0;
    valv[k] = ok ? vv[e] : 0.f;
    if (ok) atomicAdd(&hist[rowv[k] >> 9], 1);
  }
  __syncthreads();

  // exclusive scan of 196 bucket counts (256-lane Hillis-Steele)
  if (tid < 256) sd[0][tid] = (tid < NBG) ? hist[tid] : 0;
  __syncthreads();
  int c = 0;
  for (int off = 1; off < 256; off <<= 1) {
    if (tid < 256) {
      int nv = sd[c][tid];
      if (tid >= off) nv += sd[c][tid - off];
      sd[c ^ 1][tid] = nv;
    }
    __syncthreads();
    c ^= 1;
  }
  if (tid < NBG) {
    int cn = hist[tid];
    int excl = sd[c][tid] - cn;
    lbase[tid] = excl;
    cur[tid] = excl;
    gstart[tid] = cn ? atomicAdd(&gcur[g * NBG + tid], cn) : 0;
  }
  __syncthreads();

  // scatter registers -> LDS staging (bucket-ordered), record bucket id per slot
#pragma unroll
  for (int k = 0; k < SC_CHUNK / SC_THREADS; k++) {
    if (rowv[k] >= 0) {
      int b = rowv[k] >> 9;
      int p = atomicAdd(&cur[b], 1);
      stage[p] = make_int2(((rowv[k] & (RPB - 1)) << 17) | colv[k], __float_as_int(valv[k]));
      bid[p] = (unsigned char)b;
    }
  }
  __syncthreads();

  // linear sweep -> coalesced global writes into the bucket's CAP region
  for (int i = tid; i < cnt_blk; i += SC_THREADS) {
    int b = bid[i];
    int pos = gstart[b] + (i - lbase[b]);
    if (pos < CAP)  // statistically impossible overflow; memory-safety guard
      edges[(size_t)(g * NBG + b) * CAP + pos] = stage[i];
  }
}

// ---------------- pass B: in-bucket counting sort + per-row (start,end) -------
__global__ __launch_bounds__(512) void k_bucket_sort(const int* __restrict__ gcur,
                                                     int2* __restrict__ edges,
                                                     int* __restrict__ rps_all,
                                                     int* __restrict__ rpe_all) {
  __shared__ int2 stage[CAP];   // 70.7 KB
  __shared__ int hist[RPB];
  __shared__ int sd[2][RPB];
  __shared__ int cur[RPB];
  int g = blockIdx.y, b = blockIdx.x;
  int tid = threadIdx.x;
  int idx = g * NBG + b;
  size_t base = (size_t)idx * CAP;
  int count = gcur[idx];
  if (count > CAP) count = CAP;
  hist[tid] = 0;
  __syncthreads();

  const int KSL = (CAP + 511) / 512;   // 18 slots/thread
  int2 ev[KSL];
#pragma unroll
  for (int k = 0; k < KSL; k++) {
    int i = tid + k * 512;
    if (i < count) {
      ev[k] = edges[base + i];
      atomicAdd(&hist[ev[k].x >> 17], 1);
    }
  }
  __syncthreads();

  int v = hist[tid];
  sd[0][tid] = v;
  __syncthreads();
  int c2 = 0;
  for (int off = 1; off < 512; off <<= 1) {
    int nv = sd[c2][tid];
    if (tid >= off) nv += sd[c2][tid - off];
    sd[c2 ^ 1][tid] = nv;
    __syncthreads();
    c2 ^= 1;
  }
  int excl = sd[c2][tid] - v;
  int row = b * RPB + tid;
  if (row < NNODES) {
    rps_all[g * NNODES + row] = (int)base + excl;
    rpe_all[g * NNODES + row] = (int)base + excl + v;
  }
  cur[tid] = excl;
  __syncthreads();

#pragma unroll
  for (int k = 0; k < KSL; k++) {
    int i = tid + k * 512;
    if (i < count) {
      int lr = ev[k].x >> 17;
      int p = atomicAdd(&cur[lr], 1);
      stage[p] = make_int2(ev[k].x & 0x1FFFF, ev[k].y);  // strip row bits: col only
    }
  }
  __syncthreads();

  for (int i = tid; i < count; i += 512) edges[base + i] = stage[i];
}

// ---------------- prep ----------------
__global__ __launch_bounds__(256) void k_convert_bf16(const float* __restrict__ src,
                                                      unsigned short* __restrict__ dst,
                                                      int n4) {
  int i = blockIdx.x * blockDim.x + threadIdx.x;
  if (i < n4) {
    float4 v = ((const float4*)src)[i];
    ushort4 o;
    o.x = f2bf(v.x); o.y = f2bf(v.y); o.z = f2bf(v.z); o.w = f2bf(v.w);
    ((ushort4*)dst)[i] = o;
  }
}

__global__ __launch_bounds__(256) void k_transpose3(const float* __restrict__ s0,
                                                    const float* __restrict__ s1,
                                                    const float* __restrict__ s2,
                                                    unsigned short* __restrict__ d0,
                                                    unsigned short* __restrict__ d1,
                                                    unsigned short* __restrict__ d2,
                                                    int K, int N) {
  int g = blockIdx.y;
  const float* src = (g == 0) ? s0 : (g == 1 ? s1 : s2);
  unsigned short* dst = (g == 0) ? d0 : (g == 1 ? d1 : d2);
  int idx = blockIdx.x * 256 + threadIdx.x;
  if (idx < K * N) {
    int k = idx / N, n = idx % N;
    dst[(size_t)n * K + k] = f2bf(src[idx]);
  }
}

// ---------------- batched bf16 MFMA GEMMs ----------------
__global__ __launch_bounds__(256) void k_gemm1_b(const unsigned short* __restrict__ A,
                                                 const unsigned short* __restrict__ WtA,
                                                 unsigned short* __restrict__ C3, int M) {
  int bxy = blockIdx.x;
  int g = bxy % 3;
  int bx = bxy / 3;
  const unsigned short* Wt = WtA + (size_t)g * HID * FEAT;
  unsigned short* C = C3 + (size_t)g * M * HID;
  int tid = threadIdx.x;
  int wave = tid >> 6, lane = tid & 63;
  int quad = lane >> 4, r = lane & 15;
  int m0 = bx * 128 + wave * 32;
  int ra0 = m0 + r;      if (ra0 >= M) ra0 = 0;
  int ra1 = m0 + 16 + r; if (ra1 >= M) ra1 = 0;
  const unsigned short* pa0 = A + (size_t)ra0 * FEAT + quad * 8;
  const unsigned short* pa1 = A + (size_t)ra1 * FEAT + quad * 8;
  f32x4 acc[2][8];
#pragma unroll
  for (int i = 0; i < 2; i++)
#pragma unroll
    for (int j = 0; j < 8; j++) acc[i][j] = (f32x4){0.f, 0.f, 0.f, 0.f};
  for (int k0 = 0; k0 < FEAT; k0 += 32) {
    bf16x8 a0 = *(const bf16x8*)(pa0 + k0);
    bf16x8 a1 = *(const bf16x8*)(pa1 + k0);
#pragma unroll
    for (int nt = 0; nt < 8; nt++) {
      bf16x8 b = *(const bf16x8*)(Wt + (size_t)(nt * 16 + r) * FEAT + k0 + quad * 8);
      acc[0][nt] = __builtin_amdgcn_mfma_f32_16x16x32_bf16(a0, b, acc[0][nt], 0, 0, 0);
      acc[1][nt] = __builtin_amdgcn_mfma_f32_16x16x32_bf16(a1, b, acc[1][nt], 0, 0, 0);
    }
  }
#pragma unroll
  for (int t = 0; t < 2; t++)
#pragma unroll
    for (int reg = 0; reg < 4; reg++) {
      int row = m0 + t * 16 + quad * 4 + reg;
      if (row < M) {
#pragma unroll
        for (int nt = 0; nt < 8; nt++)
          C[(size_t)row * HID + nt * 16 + r] = f2bf(acc[t][nt][reg]);
      }
    }
}

__global__ __launch_bounds__(256) void k_gemm2_b(const unsigned short* __restrict__ A3,
                                                 const unsigned short* __restrict__ WtA,
                                                 unsigned short* __restrict__ C3, int M) {
  int g = blockIdx.y;
  const unsigned short* A = A3 + (size_t)g * M * HID;
  const unsigned short* Wt = WtA + (size_t)g * NCLS * HID;
  unsigned short* C = C3 + (size_t)g * M * NCLS;
  int tid = threadIdx.x;
  int wave = tid >> 6, lane = tid & 63;
  int quad = lane >> 4, r = lane & 15;
  int m0 = blockIdx.x * 128 + wave * 32;
  int ra0 = m0 + r;      if (ra0 >= M) ra0 = 0;
  int ra1 = m0 + 16 + r; if (ra1 >= M) ra1 = 0;
  const unsigned short* pa0 = A + (size_t)ra0 * HID + quad * 8;
  const unsigned short* pa1 = A + (size_t)ra1 * HID + quad * 8;
  f32x4 acc[2][4];
#pragma unroll
  for (int i = 0; i < 2; i++)
#pragma unroll
    for (int j = 0; j < 4; j++) acc[i][j] = (f32x4){0.f, 0.f, 0.f, 0.f};
  for (int k0 = 0; k0 < HID; k0 += 32) {
    bf16x8 a0 = *(const bf16x8*)(pa0 + k0);
    bf16x8 a1 = *(const bf16x8*)(pa1 + k0);
#pragma unroll
    for (int nt = 0; nt < 4; nt++) {
      bf16x8 b = *(const bf16x8*)(Wt + (size_t)(nt * 16 + r) * HID + k0 + quad * 8);
      acc[0][nt] = __builtin_amdgcn_mfma_f32_16x16x32_bf16(a0, b, acc[0][nt], 0, 0, 0);
      acc[1][nt] = __builtin_amdgcn_mfma_f32_16x16x32_bf16(a1, b, acc[1][nt], 0, 0, 0);
    }
  }
#pragma unroll
  for (int t = 0; t < 2; t++)
#pragma unroll
    for (int reg = 0; reg < 4; reg++) {
      int row = m0 + t * 16 + quad * 4 + reg;
      if (row < M) {
#pragma unroll
        for (int nt = 0; nt < 4; nt++)
          C[(size_t)row * NCLS + nt * 16 + r] = f2bf(acc[t][nt][reg]);
      }
    }
}

// ---------------- SpMM (HID=128), batched over g; 4 gather chains in flight ----
__global__ __launch_bounds__(256) void k_spmm128_b(const int* __restrict__ rps_all,
                                                   const int* __restrict__ rpe_all,
                                                   const int2* __restrict__ edges,
                                                   const unsigned short* __restrict__ dense3,
                                                   unsigned short* __restrict__ out3, int n) {
  int g = blockIdx.y;
  const int* rs = rps_all + (size_t)g * NNODES;
  const int* re = rpe_all + (size_t)g * NNODES;
  const unsigned short* dense = dense3 + (size_t)g * NNODES * HID;
  unsigned short* out = out3 + (size_t)g * NNODES * HID;
  int w = (blockIdx.x * blockDim.x + threadIdx.x) >> 6;
  int lane = threadIdx.x & 63;
  if (w >= n) return;
  int grp = lane >> 4;    // 0..3: edge slot
  int sub = lane & 15;    // feats sub*8 .. sub*8+7
  int s = rs[w], e = re[w];
  f32x2 a[4][4];
#pragma unroll
  for (int t = 0; t < 4; t++)
#pragma unroll
    for (int q = 0; q < 4; q++) a[t][q] = (f32x2){0.f, 0.f};
  for (int j = s; j < e; j += 16) {
    uint4 u[4];
    float f[4];
#pragma unroll
    for (int t = 0; t < 4; t++) {
      int ej = j + t * 4 + grp;
      bool ok = ej < e;
      int2 dd = edges[ok ? ej : s];
      u[t] = *(const uint4*)(dense + (size_t)dd.x * HID + sub * 8);
      f[t] = ok ? __int_as_float(dd.y) : 0.f;
    }
#pragma unroll
    for (int t = 0; t < 4; t++) {
      f32x2 vv; vv.x = f[t]; vv.y = f[t];
      fma8(u[t], vv, a[t]);
    }
  }
  unsigned int pk[4];
#pragma unroll
  for (int q = 0; q < 4; q++) {
    float lo = (a[0][q].x + a[1][q].x) + (a[2][q].x + a[3][q].x);
    float hi = (a[0][q].y + a[1][q].y) + (a[2][q].y + a[3][q].y);
    lo += __shfl_xor(lo, 32, 64); lo += __shfl_xor(lo, 16, 64);
    hi += __shfl_xor(hi, 32, 64); hi += __shfl_xor(hi, 16, 64);
    lo = fmaxf(lo, 0.f); hi = fmaxf(hi, 0.f);
    pk[q] = (unsigned int)f2bf(lo) | ((unsigned int)f2bf(hi) << 16);
  }
  if (lane < 16) {
    uint4 o; o.x = pk[0]; o.y = pk[1]; o.z = pk[2]; o.w = pk[3];
    *(uint4*)(out + (size_t)w * HID + sub * 8) = o;
  }
}

// ---------------- fused final SpMM (NCLS=64): 3 graphs + bias/gate + log_softmax
__global__ __launch_bounds__(256) void k_spmm64_final(const int* __restrict__ rps_all,
                                                      const int* __restrict__ rpe_all,
                                                      const int2* __restrict__ edges,
                                                      const unsigned short* __restrict__ dense3,
                                                      const float* __restrict__ b0p,
                                                      const float* __restrict__ b1p,
                                                      const float* __restrict__ b2p,
                                                      const float* __restrict__ gate,
                                                      float* __restrict__ outp, int n) {
  int w = (blockIdx.x * blockDim.x + threadIdx.x) >> 6;
  int lane = threadIdx.x & 63;
  if (w >= n) return;
  int grp = lane >> 3;    // 0..7: edge slot
  int sub = lane & 7;     // classes sub*8 .. sub*8+7
  float gv = gate[0];
  float omg = 1.0f - gv;
  // bias seed: gv*b0 + (1-gv)*(b1+b2)
  float tot[8];
  {
    float4 x0 = *(const float4*)(b0p + sub * 8), x1 = *(const float4*)(b0p + sub * 8 + 4);
    float4 y0 = *(const float4*)(b1p + sub * 8), y1 = *(const float4*)(b1p + sub * 8 + 4);
    float4 z0 = *(const float4*)(b2p + sub * 8), z1 = *(const float4*)(b2p + sub * 8 + 4);
    tot[0] = gv * x0.x + omg * (y0.x + z0.x); tot[1] = gv * x0.y + omg * (y0.y + z0.y);
    tot[2] = gv * x0.z + omg * (y0.z + z0.z); tot[3] = gv * x0.w + omg * (y0.w + z0.w);
    tot[4] = gv * x1.x + omg * (y1.x + z1.x); tot[5] = gv * x1.y + omg * (y1.y + z1.y);
    tot[6] = gv * x1.z + omg * (y1.z + z1.z); tot[7] = gv * x1.w + omg * (y1.w + z1.w);
  }
  for (int g = 0; g < 3; g++) {
    const int* rs = rps_all + (size_t)g * NNODES;
    const int* re = rpe_all + (size_t)g * NNODES;
    const unsigned short* dense = dense3 + (size_t)g * NNODES * NCLS;
    int s = rs[w], e = re[w];
    f32x2 a0[4], a1[4];
#pragma unroll
    for (int q = 0; q < 4; q++) { a0[q] = (f32x2){0.f, 0.f}; a1[q] = (f32x2){0.f, 0.f}; }
    for (int j = s; j < e; j += 16) {
      int e0 = j + grp, e1 = j + 8 + grp;
      bool k0 = e0 < e, k1 = e1 < e;
      int2 d0 = edges[k0 ? e0 : s];
      int2 d1 = edges[k1 ? e1 : s];
      uint4 u0 = *(const uint4*)(dense + (size_t)d0.x * NCLS + sub * 8);
      uint4 u1 = *(const uint4*)(dense + (size_t)d1.x * NCLS + sub * 8);
      float f0 = k0 ? __int_as_float(d0.y) : 0.f;
      float f1 = k1 ? __int_as_float(d1.y) : 0.f;
      f32x2 v0; v0.x = f0; v0.y = f0;
      f32x2 v1; v1.x = f1; v1.y = f1;
      fma8(u0, v0, a0);
      fma8(u1, v1, a1);
    }
    float scale = (g == 0) ? gv : omg;
#pragma unroll
    for (int q = 0; q < 4; q++) {
      float lo = a0[q].x + a1[q].x;
      float hi = a0[q].y + a1[q].y;
      lo += __shfl_xor(lo, 32, 64); lo += __shfl_xor(lo, 16, 64); lo += __shfl_xor(lo, 8, 64);
      hi += __shfl_xor(hi, 32, 64); hi += __shfl_xor(hi, 16, 64); hi += __shfl_xor(hi, 8, 64);
      tot[2 * q] += scale * lo;
      tot[2 * q + 1] += scale * hi;
    }
  }
  // fused log_softmax over 64 classes (8 local + shfl across sub bits 0-2)
  float m = tot[0];
#pragma unroll
  for (int i = 1; i < 8; i++) m = fmaxf(m, tot[i]);
  m = fmaxf(m, __shfl_xor(m, 1, 64));
  m = fmaxf(m, __shfl_xor(m, 2, 64));
  m = fmaxf(m, __shfl_xor(m, 4, 64));
  float sum = 0.f;
#pragma unroll
  for (int i = 0; i < 8; i++) sum += expf(tot[i] - m);
  sum += __shfl_xor(sum, 1, 64);
  sum += __shfl_xor(sum, 2, 64);
  sum += __shfl_xor(sum, 4, 64);
  float ls = m + logf(sum);
  if (grp == 0) {
    size_t o = (size_t)w * NCLS + sub * 8;
    *(float4*)(outp + o)     = make_float4(tot[0] - ls, tot[1] - ls, tot[2] - ls, tot[3] - ls);
    *(float4*)(outp + o + 4) = make_float4(tot[4] - ls, tot[5] - ls, tot[6] - ls, tot[7] - ls);
  }
}

extern "C" void kernel_launch(void* const* d_in, const int* in_sizes, int n_in,
                              void* d_out, int out_size, void* d_ws, size_t ws_size,
                              hipStream_t stream) {
  (void)in_sizes; (void)n_in; (void)out_size; (void)ws_size;
  const float* x = (const float*)d_in[0];
  const int*   rows[3]   = {(const int*)d_in[1], (const int*)d_in[4], (const int*)d_in[7]};
  const int*   colsIn[3] = {(const int*)d_in[2], (const int*)d_in[5], (const int*)d_in[8]};
  const float* valsIn[3] = {(const float*)d_in[3], (const float*)d_in[6], (const float*)d_in[9]};
  const float* Whid[3] = {(const float*)d_in[10], (const float*)d_in[13], (const float*)d_in[16]};
  const float* Wout[3] = {(const float*)d_in[11], (const float*)d_in[14], (const float*)d_in[17]};
  const float* bout[3] = {(const float*)d_in[12], (const float*)d_in[15], (const float*)d_in[18]};
  const float* gate = (const float*)d_in[19];
  float* out = (float*)d_out;

  const int N = NNODES, E = NEDGES;
  size_t off = 0;
  auto ws = [&](size_t bytes) {
    void* p = (char*)d_ws + off;
    off += (bytes + 255) & ~(size_t)255;
    return p;
  };
  // Region R1 (76.8 MB): x_bf early; h1[3] later (aliased; x_bf dead after gemm1).
  unsigned short* R1 = (unsigned short*)ws((size_t)3 * N * HID * 2);
  unsigned short* x_bf = R1;
  unsigned short* h13  = R1;
  // hsup3: gemm1 output; later reused as gemm2 output (h2) per g.
  unsigned short* hsup3 = (unsigned short*)ws((size_t)3 * N * HID * 2);
  unsigned short* Wt1a = (unsigned short*)ws((size_t)3 * HID * FEAT * 2);
  unsigned short* Wt2a = (unsigned short*)ws((size_t)3 * NCLS * HID * 2);
  int2* edges   = (int2*)ws((size_t)NB3 * CAP * 8);      // padded bucket regions
  int*  rps_all = (int*) ws((size_t)3 * N * 4);
  int*  rpe_all = (int*) ws((size_t)3 * N * 4);
  int*  gcur    = (int*) ws(NB3 * 4);

  dim3 b256(256);
  dim3 gRows3((N + 3) / 4, 3);
  int nbGemm = (N + 127) / 128;

  k_convert_bf16<<<(N * FEAT / 4 + 255) / 256, b256, 0, stream>>>(x, x_bf, N * FEAT / 4);
  k_transpose3<<<dim3((FEAT * HID + 255) / 256, 3), b256, 0, stream>>>(
      Whid[0], Whid[1], Whid[2], Wt1a, Wt1a + (size_t)HID * FEAT, Wt1a + (size_t)2 * HID * FEAT,
      FEAT, HID);
  k_transpose3<<<dim3((HID * NCLS + 255) / 256, 3), b256, 0, stream>>>(
      Wout[0], Wout[1], Wout[2], Wt2a, Wt2a + (size_t)NCLS * HID, Wt2a + (size_t)2 * NCLS * HID,
      HID, NCLS);

  // CSR build: single scatter pass into CAP-padded buckets, then in-bucket sort
  hipMemsetAsync(gcur, 0, NB3 * 4, stream);
  k_bucket_scatter<<<dim3((E + SC_CHUNK - 1) / SC_CHUNK, 3), dim3(SC_THREADS), 0, stream>>>(
      rows[0], rows[1], rows[2], colsIn[0], colsIn[1], colsIn[2],
      valsIn[0], valsIn[1], valsIn[2], gcur, edges);
  k_bucket_sort<<<dim3(NBG, 3), 512, 0, stream>>>(gcur, edges, rps_all, rpe_all);

  k_gemm1_b<<<dim3(3 * nbGemm), b256, 0, stream>>>(x_bf, Wt1a, hsup3, N);
  k_spmm128_b<<<gRows3, b256, 0, stream>>>(rps_all, rpe_all, edges, hsup3, h13, N);
  k_gemm2_b<<<dim3(nbGemm, 3), b256, 0, stream>>>(h13, Wt2a, hsup3, N);
  k_spmm64_final<<<gRows3.x == 0 ? dim3(1) : dim3((N + 3) / 4), b256, 0, stream>>>(
      rps_all, rpe_all, edges, hsup3, bout[0], bout[1], bout[2], gate, out, N);
}

// Round 6
// 746.917 us; speedup vs baseline: 1.1458x; 1.0082x over previous
//
#include <hip/hip_runtime.h>
#include <math.h>

#define NNODES 100000
#define NEDGES 1600000
#define FEAT 256
#define HID 128
#define NCLS 64
#define RPB 512                 // rows per bucket
#define NBG 196                 // buckets per graph = ceil(100000/512)
#define NB3 (3 * NBG)           // 588
#define CAP 8832                // raw per-bucket capacity (mean 8163 + 7 sigma)
#define CAPP 12416              // padded capacity: CAP + 512 rows * 7 max pad
#define SC_CHUNK 8192           // edges per scatter block (LDS-staged)
#define SC_THREADS 1024         // 16 waves/block

typedef __attribute__((ext_vector_type(8))) short bf16x8;
typedef __attribute__((ext_vector_type(4))) float f32x4;
typedef __attribute__((ext_vector_type(2))) float f32x2;

__device__ __forceinline__ float bf2f(unsigned int u16) {
  union { unsigned int i; float f; } c; c.i = u16 << 16; return c.f;
}
__device__ __forceinline__ unsigned short f2bf(float f) {
  union { float f; unsigned int i; } c; c.f = f;
  unsigned int u = c.i;
  return (unsigned short)((u + 0x7fffu + ((u >> 16) & 1u)) >> 16);  // RNE
}

// 8 bf16 (as uint4) * scalar-pair vv -> 4 packed f32x2 accumulators
__device__ __forceinline__ void fma8(const uint4 u, const f32x2 vv, f32x2* a) {
  f32x2 p0, p1, p2, p3;
  p0.x = __uint_as_float(u.x << 16); p0.y = __uint_as_float(u.x & 0xffff0000u);
  p1.x = __uint_as_float(u.y << 16); p1.y = __uint_as_float(u.y & 0xffff0000u);
  p2.x = __uint_as_float(u.z << 16); p2.y = __uint_as_float(u.z & 0xffff0000u);
  p3.x = __uint_as_float(u.w << 16); p3.y = __uint_as_float(u.w & 0xffff0000u);
  a[0] += p0 * vv; a[1] += p1 * vv; a[2] += p2 * vv; a[3] += p3 * vv;
}

// ---------------- pass A: bucket scatter into fixed CAPP-slot regions ----------
// No prescan: each block reserves per-bucket space with one global atomic;
// bucket b of graph g occupies edges[(g*NBG+b)*CAPP ... +CAPP).
__global__ __launch_bounds__(SC_THREADS) void k_bucket_scatter(
    const int* __restrict__ r0, const int* __restrict__ r1, const int* __restrict__ r2,
    const int* __restrict__ c0, const int* __restrict__ c1, const int* __restrict__ c2,
    const float* __restrict__ v0, const float* __restrict__ v1, const float* __restrict__ v2,
    int* __restrict__ gcur, int2* __restrict__ edges) {
  __shared__ int2 stage[SC_CHUNK];            // 64 KB
  __shared__ unsigned char bid[SC_CHUNK];     // 8 KB  (NBG=196 < 256)
  __shared__ int hist[NBG];
  __shared__ int lbase[NBG];
  __shared__ int gstart[NBG];
  __shared__ int cur[NBG];
  __shared__ int sd[2][256];
  int g = blockIdx.y;
  const int*   rr = (g == 0) ? r0 : (g == 1 ? r1 : r2);
  const int*   cc = (g == 0) ? c0 : (g == 1 ? c1 : c2);
  const float* vv = (g == 0) ? v0 : (g == 1 ? v1 : v2);
  int tid = threadIdx.x;
  int base = blockIdx.x * SC_CHUNK;
  int cnt_blk = NEDGES - base;
  if (cnt_blk > SC_CHUNK) cnt_blk = SC_CHUNK;

  for (int i = tid; i < NBG; i += SC_THREADS) hist[i] = 0;
  __syncthreads();

  int rowv[SC_CHUNK / SC_THREADS];
  int colv[SC_CHUNK / SC_THREADS];
  float valv[SC_CHUNK / SC_THREADS];
#pragma unroll
  for (int k = 0; k < SC_CHUNK / SC_THREADS; k++) {
    int e = base + k * SC_THREADS + tid;
    bool ok = e < NEDGES;
    rowv[k] = ok ? rr[e] : -1;
    colv[k] = ok ? cc[e] : 0;
    valv[k] = ok ? vv[e] : 0.f;
    if (ok) atomicAdd(&hist[rowv[k] >> 9], 1);
  }
  __syncthreads();

  // exclusive scan of 196 bucket counts (256-lane Hillis-Steele)
  if (tid < 256) sd[0][tid] = (tid < NBG) ? hist[tid] : 0;
  __syncthreads();
  int c = 0;
  for (int off = 1; off < 256; off <<= 1) {
    if (tid < 256) {
      int nv = sd[c][tid];
      if (tid >= off) nv += sd[c][tid - off];
      sd[c ^ 1][tid] = nv;
    }
    __syncthreads();
    c ^= 1;
  }
  if (tid < NBG) {
    int cn = hist[tid];
    int excl = sd[c][tid] - cn;
    lbase[tid] = excl;
    cur[tid] = excl;
    gstart[tid] = cn ? atomicAdd(&gcur[g * NBG + tid], cn) : 0;
  }
  __syncthreads();

  // scatter registers -> LDS staging (bucket-ordered), record bucket id per slot
#pragma unroll
  for (int k = 0; k < SC_CHUNK / SC_THREADS; k++) {
    if (rowv[k] >= 0) {
      int b = rowv[k] >> 9;
      int p = atomicAdd(&cur[b], 1);
      stage[p] = make_int2(((rowv[k] & (RPB - 1)) << 17) | colv[k], __float_as_int(valv[k]));
      bid[p] = (unsigned char)b;
    }
  }
  __syncthreads();

  // linear sweep -> coalesced global writes into the bucket's CAPP region
  for (int i = tid; i < cnt_blk; i += SC_THREADS) {
    int b = bid[i];
    int pos = gstart[b] + (i - lbase[b]);
    if (pos < CAPP)  // statistically impossible overflow; memory-safety guard
      edges[(size_t)(g * NBG + b) * CAPP + pos] = stage[i];
  }
}

// ---------------- pass B: in-bucket counting sort, rows PADDED to x8 ----------
// Each row's edge list is padded to a multiple of 8 with {col=0,val=0} entries
// so SpMM inner loops need no per-lane validity masks (pads contribute 0).
__global__ __launch_bounds__(512) void k_bucket_sort(const int* __restrict__ gcur,
                                                     int2* __restrict__ edges,
                                                     int* __restrict__ rps_all,
                                                     int* __restrict__ rpe_all) {
  __shared__ int2 stage[CAPP];  // 99.3 KB
  __shared__ int hist[RPB];
  __shared__ int sd[2][RPB];
  __shared__ int cur[RPB];
  __shared__ int ptot_s;
  int g = blockIdx.y, b = blockIdx.x;
  int tid = threadIdx.x;
  int idx = g * NBG + b;
  size_t base = (size_t)idx * CAPP;
  int count = gcur[idx];
  if (count > CAPP) count = CAPP;
  hist[tid] = 0;
  __syncthreads();

  const int KSL = (CAPP + 511) / 512;   // 25 slots/thread
  int2 ev[KSL];
#pragma unroll
  for (int k = 0; k < KSL; k++) {
    int i = tid + k * 512;
    if (i < count) {
      ev[k] = edges[base + i];
      atomicAdd(&hist[ev[k].x >> 17], 1);
    }
  }
  __syncthreads();

  int v = hist[tid];
  int pv = (v + 7) & ~7;            // padded row length (multiple of 8)
  sd[0][tid] = pv;
  __syncthreads();
  int c2 = 0;
  for (int off = 1; off < 512; off <<= 1) {
    int nv = sd[c2][tid];
    if (tid >= off) nv += sd[c2][tid - off];
    sd[c2 ^ 1][tid] = nv;
    __syncthreads();
    c2 ^= 1;
  }
  int pexcl = sd[c2][tid] - pv;
  if (tid == 511) ptot_s = sd[c2][511];
  int row = b * RPB + tid;
  if (row < NNODES) {
    rps_all[g * NNODES + row] = (int)base + pexcl;
    rpe_all[g * NNODES + row] = (int)base + pexcl + pv;   // padded end
  }
  cur[tid] = pexcl;
  __syncthreads();

#pragma unroll
  for (int k = 0; k < KSL; k++) {
    int i = tid + k * 512;
    if (i < count) {
      int lr = ev[k].x >> 17;
      int p = atomicAdd(&cur[lr], 1);
      if (p < CAPP) stage[p] = make_int2(ev[k].x & 0x1FFFF, ev[k].y);  // col only
    }
  }
  // fill pad slots for this thread's row
  for (int i = pexcl + v; i < pexcl + pv; i++)
    if (i < CAPP) stage[i] = make_int2(0, 0);
  __syncthreads();

  int ptot = ptot_s;
  if (ptot > CAPP) ptot = CAPP;
  for (int i = tid; i < ptot; i += 512) edges[base + i] = stage[i];
}

// ---------------- prep ----------------
__global__ __launch_bounds__(256) void k_convert_bf16(const float* __restrict__ src,
                                                      unsigned short* __restrict__ dst,
                                                      int n4) {
  int i = blockIdx.x * blockDim.x + threadIdx.x;
  if (i < n4) {
    float4 v = ((const float4*)src)[i];
    ushort4 o;
    o.x = f2bf(v.x); o.y = f2bf(v.y); o.z = f2bf(v.z); o.w = f2bf(v.w);
    ((ushort4*)dst)[i] = o;
  }
}

__global__ __launch_bounds__(256) void k_transpose3(const float* __restrict__ s0,
                                                    const float* __restrict__ s1,
                                                    const float* __restrict__ s2,
                                                    unsigned short* __restrict__ d0,
                                                    unsigned short* __restrict__ d1,
                                                    unsigned short* __restrict__ d2,
                                                    int K, int N) {
  int g = blockIdx.y;
  const float* src = (g == 0) ? s0 : (g == 1 ? s1 : s2);
  unsigned short* dst = (g == 0) ? d0 : (g == 1 ? d1 : d2);
  int idx = blockIdx.x * 256 + threadIdx.x;
  if (idx < K * N) {
    int k = idx / N, n = idx % N;
    dst[(size_t)n * K + k] = f2bf(src[idx]);
  }
}

// ---------------- batched bf16 MFMA GEMMs ----------------
__global__ __launch_bounds__(256) void k_gemm1_b(const unsigned short* __restrict__ A,
                                                 const unsigned short* __restrict__ WtA,
                                                 unsigned short* __restrict__ C3, int M) {
  int bxy = blockIdx.x;
  int g = bxy % 3;
  int bx = bxy / 3;
  const unsigned short* Wt = WtA + (size_t)g * HID * FEAT;
  unsigned short* C = C3 + (size_t)g * M * HID;
  int tid = threadIdx.x;
  int wave = tid >> 6, lane = tid & 63;
  int quad = lane >> 4, r = lane & 15;
  int m0 = bx * 128 + wave * 32;
  int ra0 = m0 + r;      if (ra0 >= M) ra0 = 0;
  int ra1 = m0 + 16 + r; if (ra1 >= M) ra1 = 0;
  const unsigned short* pa0 = A + (size_t)ra0 * FEAT + quad * 8;
  const unsigned short* pa1 = A + (size_t)ra1 * FEAT + quad * 8;
  f32x4 acc[2][8];
#pragma unroll
  for (int i = 0; i < 2; i++)
#pragma unroll
    for (int j = 0; j < 8; j++) acc[i][j] = (f32x4){0.f, 0.f, 0.f, 0.f};
  for (int k0 = 0; k0 < FEAT; k0 += 32) {
    bf16x8 a0 = *(const bf16x8*)(pa0 + k0);
    bf16x8 a1 = *(const bf16x8*)(pa1 + k0);
#pragma unroll
    for (int nt = 0; nt < 8; nt++) {
      bf16x8 b = *(const bf16x8*)(Wt + (size_t)(nt * 16 + r) * FEAT + k0 + quad * 8);
      acc[0][nt] = __builtin_amdgcn_mfma_f32_16x16x32_bf16(a0, b, acc[0][nt], 0, 0, 0);
      acc[1][nt] = __builtin_amdgcn_mfma_f32_16x16x32_bf16(a1, b, acc[1][nt], 0, 0, 0);
    }
  }
#pragma unroll
  for (int t = 0; t < 2; t++)
#pragma unroll
    for (int reg = 0; reg < 4; reg++) {
      int row = m0 + t * 16 + quad * 4 + reg;
      if (row < M) {
#pragma unroll
        for (int nt = 0; nt < 8; nt++)
          C[(size_t)row * HID + nt * 16 + r] = f2bf(acc[t][nt][reg]);
      }
    }
}

__global__ __launch_bounds__(256) void k_gemm2_b(const unsigned short* __restrict__ A3,
                                                 const unsigned short* __restrict__ WtA,
                                                 unsigned short* __restrict__ C3, int M) {
  int g = blockIdx.y;
  const unsigned short* A = A3 + (size_t)g * M * HID;
  const unsigned short* Wt = WtA + (size_t)g * NCLS * HID;
  unsigned short* C = C3 + (size_t)g * M * NCLS;
  int tid = threadIdx.x;
  int wave = tid >> 6, lane = tid & 63;
  int quad = lane >> 4, r = lane & 15;
  int m0 = blockIdx.x * 128 + wave * 32;
  int ra0 = m0 + r;      if (ra0 >= M) ra0 = 0;
  int ra1 = m0 + 16 + r; if (ra1 >= M) ra1 = 0;
  const unsigned short* pa0 = A + (size_t)ra0 * HID + quad * 8;
  const unsigned short* pa1 = A + (size_t)ra1 * HID + quad * 8;
  f32x4 acc[2][4];
#pragma unroll
  for (int i = 0; i < 2; i++)
#pragma unroll
    for (int j = 0; j < 4; j++) acc[i][j] = (f32x4){0.f, 0.f, 0.f, 0.f};
  for (int k0 = 0; k0 < HID; k0 += 32) {
    bf16x8 a0 = *(const bf16x8*)(pa0 + k0);
    bf16x8 a1 = *(const bf16x8*)(pa1 + k0);
#pragma unroll
    for (int nt = 0; nt < 4; nt++) {
      bf16x8 b = *(const bf16x8*)(Wt + (size_t)(nt * 16 + r) * HID + k0 + quad * 8);
      acc[0][nt] = __builtin_amdgcn_mfma_f32_16x16x32_bf16(a0, b, acc[0][nt], 0, 0, 0);
      acc[1][nt] = __builtin_amdgcn_mfma_f32_16x16x32_bf16(a1, b, acc[1][nt], 0, 0, 0);
    }
  }
#pragma unroll
  for (int t = 0; t < 2; t++)
#pragma unroll
    for (int reg = 0; reg < 4; reg++) {
      int row = m0 + t * 16 + quad * 4 + reg;
      if (row < M) {
#pragma unroll
        for (int nt = 0; nt < 4; nt++)
          C[(size_t)row * NCLS + nt * 16 + r] = f2bf(acc[t][nt][reg]);
      }
    }
}

// ---------------- SpMM (HID=128), batched over g; padded rows, no masks --------
__global__ __launch_bounds__(256) void k_spmm128_b(const int* __restrict__ rps_all,
                                                   const int* __restrict__ rpe_all,
                                                   const int2* __restrict__ edges,
                                                   const unsigned short* __restrict__ dense3,
                                                   unsigned short* __restrict__ out3, int n) {
  int g = blockIdx.y;
  const int* rs = rps_all + (size_t)g * NNODES;
  const int* re = rpe_all + (size_t)g * NNODES;
  const unsigned short* dense = dense3 + (size_t)g * NNODES * HID;
  unsigned short* out = out3 + (size_t)g * NNODES * HID;
  int w = (blockIdx.x * blockDim.x + threadIdx.x) >> 6;
  int lane = threadIdx.x & 63;
  if (w >= n) return;
  int grp = lane >> 4;    // 0..3: edge slot within chunk half
  int sub = lane & 15;    // feats sub*8 .. sub*8+7
  int s = __builtin_amdgcn_readfirstlane(rs[w]);
  int e = __builtin_amdgcn_readfirstlane(re[w]);
  f32x2 a0[4], a1[4];
#pragma unroll
  for (int q = 0; q < 4; q++) { a0[q] = (f32x2){0.f, 0.f}; a1[q] = (f32x2){0.f, 0.f}; }
  for (int j = s; j < e; j += 8) {
    int2 d0 = edges[j + grp];
    int2 d1 = edges[j + 4 + grp];
    uint4 u0 = *(const uint4*)(dense + (size_t)d0.x * HID + sub * 8);
    uint4 u1 = *(const uint4*)(dense + (size_t)d1.x * HID + sub * 8);
    f32x2 v0; v0.x = __int_as_float(d0.y); v0.y = v0.x;
    f32x2 v1; v1.x = __int_as_float(d1.y); v1.y = v1.x;
    fma8(u0, v0, a0);
    fma8(u1, v1, a1);
  }
  unsigned int pk[4];
#pragma unroll
  for (int q = 0; q < 4; q++) {
    float lo = a0[q].x + a1[q].x;
    float hi = a0[q].y + a1[q].y;
    lo += __shfl_xor(lo, 32, 64); lo += __shfl_xor(lo, 16, 64);
    hi += __shfl_xor(hi, 32, 64); hi += __shfl_xor(hi, 16, 64);
    lo = fmaxf(lo, 0.f); hi = fmaxf(hi, 0.f);
    pk[q] = (unsigned int)f2bf(lo) | ((unsigned int)f2bf(hi) << 16);
  }
  if (lane < 16) {
    uint4 o; o.x = pk[0]; o.y = pk[1]; o.z = pk[2]; o.w = pk[3];
    *(uint4*)(out + (size_t)w * HID + sub * 8) = o;
  }
}

// ---------------- fused final SpMM (NCLS=64): 3 graphs + bias/gate + log_softmax
__global__ __launch_bounds__(256) void k_spmm64_final(const int* __restrict__ rps_all,
                                                      const int* __restrict__ rpe_all,
                                                      const int2* __restrict__ edges,
                                                      const unsigned short* __restrict__ dense3,
                                                      const float* __restrict__ b0p,
                                                      const float* __restrict__ b1p,
                                                      const float* __restrict__ b2p,
                                                      const float* __restrict__ gate,
                                                      float* __restrict__ outp, int n) {
  int w = (blockIdx.x * blockDim.x + threadIdx.x) >> 6;
  int lane = threadIdx.x & 63;
  if (w >= n) return;
  int grp = lane >> 3;    // 0..7: edge slot
  int sub = lane & 7;     // classes sub*8 .. sub*8+7
  float gv = gate[0];
  float omg = 1.0f - gv;
  // bias seed: gv*b0 + (1-gv)*(b1+b2)
  float tot[8];
  {
    float4 x0 = *(const float4*)(b0p + sub * 8), x1 = *(const float4*)(b0p + sub * 8 + 4);
    float4 y0 = *(const float4*)(b1p + sub * 8), y1 = *(const float4*)(b1p + sub * 8 + 4);
    float4 z0 = *(const float4*)(b2p + sub * 8), z1 = *(const float4*)(b2p + sub * 8 + 4);
    tot[0] = gv * x0.x + omg * (y0.x + z0.x); tot[1] = gv * x0.y + omg * (y0.y + z0.y);
    tot[2] = gv * x0.z + omg * (y0.z + z0.z); tot[3] = gv * x0.w + omg * (y0.w + z0.w);
    tot[4] = gv * x1.x + omg * (y1.x + z1.x); tot[5] = gv * x1.y + omg * (y1.y + z1.y);
    tot[6] = gv * x1.z + omg * (y1.z + z1.z); tot[7] = gv * x1.w + omg * (y1.w + z1.w);
  }
  for (int g = 0; g < 3; g++) {
    const int* rs = rps_all + (size_t)g * NNODES;
    const int* re = rpe_all + (size_t)g * NNODES;
    const unsigned short* dense = dense3 + (size_t)g * NNODES * NCLS;
    int s = __builtin_amdgcn_readfirstlane(rs[w]);
    int e = __builtin_amdgcn_readfirstlane(re[w]);
    f32x2 a0[4], a1[4];
#pragma unroll
    for (int q = 0; q < 4; q++) { a0[q] = (f32x2){0.f, 0.f}; a1[q] = (f32x2){0.f, 0.f}; }
    int j = s;
    for (; j + 16 <= e; j += 16) {       // uniform 2-chain chunks, no masks
      int2 d0 = edges[j + grp];
      int2 d1 = edges[j + 8 + grp];
      uint4 u0 = *(const uint4*)(dense + (size_t)d0.x * NCLS + sub * 8);
      uint4 u1 = *(const uint4*)(dense + (size_t)d1.x * NCLS + sub * 8);
      f32x2 v0; v0.x = __int_as_float(d0.y); v0.y = v0.x;
      f32x2 v1; v1.x = __int_as_float(d1.y); v1.y = v1.x;
      fma8(u0, v0, a0);
      fma8(u1, v1, a1);
    }
    if (j < e) {                          // single trailing 8-chunk (uniform)
      int2 d0 = edges[j + grp];
      uint4 u0 = *(const uint4*)(dense + (size_t)d0.x * NCLS + sub * 8);
      f32x2 v0; v0.x = __int_as_float(d0.y); v0.y = v0.x;
      fma8(u0, v0, a0);
    }
    float scale = (g == 0) ? gv : omg;
#pragma unroll
    for (int q = 0; q < 4; q++) {
      float lo = a0[q].x + a1[q].x;
      float hi = a0[q].y + a1[q].y;
      lo += __shfl_xor(lo, 32, 64); lo += __shfl_xor(lo, 16, 64); lo += __shfl_xor(lo, 8, 64);
      hi += __shfl_xor(hi, 32, 64); hi += __shfl_xor(hi, 16, 64); hi += __shfl_xor(hi, 8, 64);
      tot[2 * q] += scale * lo;
      tot[2 * q + 1] += scale * hi;
    }
  }
  // fused log_softmax over 64 classes (8 local + shfl across sub bits 0-2)
  float m = tot[0];
#pragma unroll
  for (int i = 1; i < 8; i++) m = fmaxf(m, tot[i]);
  m = fmaxf(m, __shfl_xor(m, 1, 64));
  m = fmaxf(m, __shfl_xor(m, 2, 64));
  m = fmaxf(m, __shfl_xor(m, 4, 64));
  float sum = 0.f;
#pragma unroll
  for (int i = 0; i < 8; i++) sum += expf(tot[i] - m);
  sum += __shfl_xor(sum, 1, 64);
  sum += __shfl_xor(sum, 2, 64);
  sum += __shfl_xor(sum, 4, 64);
  float ls = m + logf(sum);
  if (grp == 0) {
    size_t o = (size_t)w * NCLS + sub * 8;
    *(float4*)(outp + o)     = make_float4(tot[0] - ls, tot[1] - ls, tot[2] - ls, tot[3] - ls);
    *(float4*)(outp + o + 4) = make_float4(tot[4] - ls, tot[5] - ls, tot[6] - ls, tot[7] - ls);
  }
}

extern "C" void kernel_launch(void* const* d_in, const int* in_sizes, int n_in,
                              void* d_out, int out_size, void* d_ws, size_t ws_size,
                              hipStream_t stream) {
  (void)in_sizes; (void)n_in; (void)out_size; (void)ws_size;
  const float* x = (const float*)d_in[0];
  const int*   rows[3]   = {(const int*)d_in[1], (const int*)d_in[4], (const int*)d_in[7]};
  const int*   colsIn[3] = {(const int*)d_in[2], (const int*)d_in[5], (const int*)d_in[8]};
  const float* valsIn[3] = {(const float*)d_in[3], (const float*)d_in[6], (const float*)d_in[9]};
  const float* Whid[3] = {(const float*)d_in[10], (const float*)d_in[13], (const float*)d_in[16]};
  const float* Wout[3] = {(const float*)d_in[11], (const float*)d_in[14], (const float*)d_in[17]};
  const float* bout[3] = {(const float*)d_in[12], (const float*)d_in[15], (const float*)d_in[18]};
  const float* gate = (const float*)d_in[19];
  float* out = (float*)d_out;

  const int N = NNODES, E = NEDGES;
  size_t off = 0;
  auto ws = [&](size_t bytes) {
    void* p = (char*)d_ws + off;
    off += (bytes + 255) & ~(size_t)255;
    return p;
  };
  // Region R1 (76.8 MB): x_bf early; h1[3] later (aliased; x_bf dead after gemm1).
  unsigned short* R1 = (unsigned short*)ws((size_t)3 * N * HID * 2);
  unsigned short* x_bf = R1;
  unsigned short* h13  = R1;
  // hsup3: gemm1 output; later reused as gemm2 output (h2) per g.
  unsigned short* hsup3 = (unsigned short*)ws((size_t)3 * N * HID * 2);
  unsigned short* Wt1a = (unsigned short*)ws((size_t)3 * HID * FEAT * 2);
  unsigned short* Wt2a = (unsigned short*)ws((size_t)3 * NCLS * HID * 2);
  int2* edges   = (int2*)ws((size_t)NB3 * CAPP * 8);     // padded bucket regions (58.4 MB)
  int*  rps_all = (int*) ws((size_t)3 * N * 4);
  int*  rpe_all = (int*) ws((size_t)3 * N * 4);
  int*  gcur    = (int*) ws(NB3 * 4);

  dim3 b256(256);
  dim3 gRows3((N + 3) / 4, 3);
  int nbGemm = (N + 127) / 128;

  k_convert_bf16<<<(N * FEAT / 4 + 255) / 256, b256, 0, stream>>>(x, x_bf, N * FEAT / 4);
  k_transpose3<<<dim3((FEAT * HID + 255) / 256, 3), b256, 0, stream>>>(
      Whid[0], Whid[1], Whid[2], Wt1a, Wt1a + (size_t)HID * FEAT, Wt1a + (size_t)2 * HID * FEAT,
      FEAT, HID);
  k_transpose3<<<dim3((HID * NCLS + 255) / 256, 3), b256, 0, stream>>>(
      Wout[0], Wout[1], Wout[2], Wt2a, Wt2a + (size_t)NCLS * HID, Wt2a + (size_t)2 * NCLS * HID,
      HID, NCLS);

  // CSR build: single scatter pass into CAPP-padded buckets, then in-bucket sort
  hipMemsetAsync(gcur, 0, NB3 * 4, stream);
  k_bucket_scatter<<<dim3((E + SC_CHUNK - 1) / SC_CHUNK, 3), dim3(SC_THREADS), 0, stream>>>(
      rows[0], rows[1], rows[2], colsIn[0], colsIn[1], colsIn[2],
      valsIn[0], valsIn[1], valsIn[2], gcur, edges);
  k_bucket_sort<<<dim3(NBG, 3), 512, 0, stream>>>(gcur, edges, rps_all, rpe_all);

  k_gemm1_b<<<dim3(3 * nbGemm), b256, 0, stream>>>(x_bf, Wt1a, hsup3, N);
  k_spmm128_b<<<gRows3, b256, 0, stream>>>(rps_all, rpe_all, edges, hsup3, h13, N);
  k_gemm2_b<<<dim3(nbGemm, 3), b256, 0, stream>>>(h13, Wt2a, hsup3, N);
  k_spmm64_final<<<dim3((N + 3) / 4), b256, 0, stream>>>(
      rps_all, rpe_all, edges, hsup3, bout[0], bout[1], bout[2], gate, out, N);
}

// Round 7
// 697.525 us; speedup vs baseline: 1.2269x; 1.0708x over previous
//
#include <hip/hip_runtime.h>
#include <math.h>

#define NNODES 100000
#define NEDGES 1600000
#define FEAT 256
#define HID 128
#define NCLS 64
#define RPB 512                 // rows per bucket
#define NBG 196                 // buckets per graph = ceil(100000/512)
#define NB3 (3 * NBG)           // 588
#define CAP 8832                // per-bucket edge capacity (mean 8163 + 7 sigma)
#define SC_CHUNK 8192           // edges per scatter block (LDS-staged)
#define SC_THREADS 1024         // 16 waves/block

typedef __attribute__((ext_vector_type(8))) short bf16x8;
typedef __attribute__((ext_vector_type(4))) float f32x4;
typedef __attribute__((ext_vector_type(2))) float f32x2;

__device__ __forceinline__ unsigned short f2bf(float f) {
  union { float f; unsigned int i; } c; c.f = f;
  unsigned int u = c.i;
  return (unsigned short)((u + 0x7fffu + ((u >> 16) & 1u)) >> 16);  // RNE
}

// 8 bf16 (as uint4) * scalar-pair vv -> 4 packed f32x2 accumulators
__device__ __forceinline__ void fma8(const uint4 u, const f32x2 vv, f32x2* a) {
  f32x2 p0, p1, p2, p3;
  p0.x = __uint_as_float(u.x << 16); p0.y = __uint_as_float(u.x & 0xffff0000u);
  p1.x = __uint_as_float(u.y << 16); p1.y = __uint_as_float(u.y & 0xffff0000u);
  p2.x = __uint_as_float(u.z << 16); p2.y = __uint_as_float(u.z & 0xffff0000u);
  p3.x = __uint_as_float(u.w << 16); p3.y = __uint_as_float(u.w & 0xffff0000u);
  a[0] += p0 * vv; a[1] += p1 * vv; a[2] += p2 * vv; a[3] += p3 * vv;
}

// ---------------- bucket histogram: bhist[g*NBG + (row>>9)] ----------------
__global__ __launch_bounds__(256) void k_bhist(const int* __restrict__ r0,
                                               const int* __restrict__ r1,
                                               const int* __restrict__ r2,
                                               int* __restrict__ bhist) {
  __shared__ int h[NBG];
  int g = blockIdx.y;
  const int* rr = (g == 0) ? r0 : (g == 1 ? r1 : r2);
  int tid = threadIdx.x;
  for (int i = tid; i < NBG; i += 256) h[i] = 0;
  __syncthreads();
  int base = blockIdx.x * 4096;
#pragma unroll
  for (int k = 0; k < 16; k++) {
    int e = base + k * 256 + tid;
    if (e < NEDGES) atomicAdd(&h[rr[e] >> 9], 1);
  }
  __syncthreads();
  for (int i = tid; i < NBG; i += 256)
    if (h[i]) atomicAdd(&bhist[g * NBG + i], h[i]);
}

// single-block exclusive scan over NB3 bucket counts -> boff[0..NB3]
__global__ __launch_bounds__(1024) void k_bscan(const int* __restrict__ bhist,
                                                int* __restrict__ boff) {
  __shared__ int sd[2][1024];
  int tid = threadIdx.x;
  int v = (tid < NB3) ? bhist[tid] : 0;
  sd[0][tid] = v;
  __syncthreads();
  int cur = 0;
  for (int off = 1; off < 1024; off <<= 1) {
    int nv = sd[cur][tid];
    if (tid >= off) nv += sd[cur][tid - off];
    sd[cur ^ 1][tid] = nv;
    __syncthreads();
    cur ^= 1;
  }
  int incl = sd[cur][tid];
  if (tid < NB3) boff[tid] = incl - v;
  if (tid == NB3 - 1) boff[NB3] = incl;
}

// ---------------- pass A: coarse bucket scatter (LDS-staged, coalesced writes) ---
__global__ __launch_bounds__(SC_THREADS) void k_bucket_scatter(
    const int* __restrict__ r0, const int* __restrict__ r1, const int* __restrict__ r2,
    const int* __restrict__ c0, const int* __restrict__ c1, const int* __restrict__ c2,
    const float* __restrict__ v0, const float* __restrict__ v1, const float* __restrict__ v2,
    int* __restrict__ gcur, int2* __restrict__ edges) {
  __shared__ int2 stage[SC_CHUNK];            // 64 KB
  __shared__ unsigned char bid[SC_CHUNK];     // 8 KB  (NBG=196 < 256)
  __shared__ int hist[NBG];
  __shared__ int lbase[NBG];
  __shared__ int gstart[NBG];
  __shared__ int cur[NBG];
  __shared__ int sd[2][256];
  int g = blockIdx.y;
  const int*   rr = (g == 0) ? r0 : (g == 1 ? r1 : r2);
  const int*   cc = (g == 0) ? c0 : (g == 1 ? c1 : c2);
  const float* vv = (g == 0) ? v0 : (g == 1 ? v1 : v2);
  int tid = threadIdx.x;
  int base = blockIdx.x * SC_CHUNK;
  int cnt_blk = NEDGES - base;
  if (cnt_blk > SC_CHUNK) cnt_blk = SC_CHUNK;

  for (int i = tid; i < NBG; i += SC_THREADS) hist[i] = 0;
  __syncthreads();

  int rowv[SC_CHUNK / SC_THREADS];
  int colv[SC_CHUNK / SC_THREADS];
  float valv[SC_CHUNK / SC_THREADS];
#pragma unroll
  for (int k = 0; k < SC_CHUNK / SC_THREADS; k++) {
    int e = base + k * SC_THREADS + tid;
    bool ok = e < NEDGES;
    rowv[k] = ok ? rr[e] : -1;
    colv[k] = ok ? cc[e] : 0;
    valv[k] = ok ? vv[e] : 0.f;
    if (ok) atomicAdd(&hist[rowv[k] >> 9], 1);
  }
  __syncthreads();

  if (tid < 256) sd[0][tid] = (tid < NBG) ? hist[tid] : 0;
  __syncthreads();
  int c = 0;
  for (int off = 1; off < 256; off <<= 1) {
    if (tid < 256) {
      int nv = sd[c][tid];
      if (tid >= off) nv += sd[c][tid - off];
      sd[c ^ 1][tid] = nv;
    }
    __syncthreads();
    c ^= 1;
  }
  if (tid < NBG) {
    int cn = hist[tid];
    int excl = sd[c][tid] - cn;
    lbase[tid] = excl;
    cur[tid] = excl;
    gstart[tid] = cn ? atomicAdd(&gcur[g * NBG + tid], cn) : 0;
  }
  __syncthreads();

#pragma unroll
  for (int k = 0; k < SC_CHUNK / SC_THREADS; k++) {
    if (rowv[k] >= 0) {
      int b = rowv[k] >> 9;
      int p = atomicAdd(&cur[b], 1);
      stage[p] = make_int2(((rowv[k] & (RPB - 1)) << 17) | colv[k], __float_as_int(valv[k]));
      bid[p] = (unsigned char)b;
    }
  }
  __syncthreads();

  for (int i = tid; i < cnt_blk; i += SC_THREADS) {
    int b = bid[i];
    int dst = gstart[b] + (i - lbase[b]);
    edges[dst] = stage[i];
  }
}

// ---------------- pass B: in-bucket counting sort (LDS scatter, coalesced IO) ---
__global__ __launch_bounds__(512) void k_bucket_sort(const int* __restrict__ boff,
                                                     int2* __restrict__ edges,
                                                     int* __restrict__ row_ptr_all) {
  __shared__ int2 stage[CAP];   // 70.7 KB
  __shared__ int hist[RPB];
  __shared__ int sd[2][RPB];
  __shared__ int cur[RPB];
  int g = blockIdx.y, b = blockIdx.x;
  int tid = threadIdx.x;
  int idx = g * NBG + b;
  int base = boff[idx];
  int count = boff[idx + 1] - base;
  if (count > CAP) count = CAP;
  hist[tid] = 0;
  __syncthreads();

  const int KSL = (CAP + 511) / 512;   // 18 slots/thread
  int2 ev[KSL];
#pragma unroll
  for (int k = 0; k < KSL; k++) {
    int i = tid + k * 512;
    if (i < count) {
      ev[k] = edges[base + i];
      atomicAdd(&hist[ev[k].x >> 17], 1);
    }
  }
  __syncthreads();

  int v = hist[tid];
  sd[0][tid] = v;
  __syncthreads();
  int c2 = 0;
  for (int off = 1; off < 512; off <<= 1) {
    int nv = sd[c2][tid];
    if (tid >= off) nv += sd[c2][tid - off];
    sd[c2 ^ 1][tid] = nv;
    __syncthreads();
    c2 ^= 1;
  }
  int excl = sd[c2][tid] - v;
  int row = b * RPB + tid;
  if (row <= NNODES) row_ptr_all[g * (NNODES + 1) + row] = base + excl;
  cur[tid] = excl;
  __syncthreads();

#pragma unroll
  for (int k = 0; k < KSL; k++) {
    int i = tid + k * 512;
    if (i < count) {
      int lr = ev[k].x >> 17;
      int p = atomicAdd(&cur[lr], 1);
      stage[p] = make_int2(ev[k].x & 0x1FFFF, ev[k].y);  // strip row bits: col only
    }
  }
  __syncthreads();

  for (int i = tid; i < count; i += 512) edges[base + i] = stage[i];
}

// ---------------- prep ----------------
__global__ __launch_bounds__(256) void k_convert_bf16(const float* __restrict__ src,
                                                      unsigned short* __restrict__ dst,
                                                      int n4) {
  int i = blockIdx.x * blockDim.x + threadIdx.x;
  if (i < n4) {
    float4 v = ((const float4*)src)[i];
    ushort4 o;
    o.x = f2bf(v.x); o.y = f2bf(v.y); o.z = f2bf(v.z); o.w = f2bf(v.w);
    ((ushort4*)dst)[i] = o;
  }
}

__global__ __launch_bounds__(256) void k_transpose3(const float* __restrict__ s0,
                                                    const float* __restrict__ s1,
                                                    const float* __restrict__ s2,
                                                    unsigned short* __restrict__ d0,
                                                    unsigned short* __restrict__ d1,
                                                    unsigned short* __restrict__ d2,
                                                    int K, int N) {
  int g = blockIdx.y;
  const float* src = (g == 0) ? s0 : (g == 1 ? s1 : s2);
  unsigned short* dst = (g == 0) ? d0 : (g == 1 ? d1 : d2);
  int idx = blockIdx.x * 256 + threadIdx.x;
  if (idx < K * N) {
    int k = idx / N, n = idx % N;
    dst[(size_t)n * K + k] = f2bf(src[idx]);
  }
}

// ---------------- batched bf16 MFMA GEMMs ----------------
__global__ __launch_bounds__(256) void k_gemm1_b(const unsigned short* __restrict__ A,
                                                 const unsigned short* __restrict__ WtA,
                                                 unsigned short* __restrict__ C3, int M) {
  int bxy = blockIdx.x;
  int g = bxy % 3;
  int bx = bxy / 3;
  const unsigned short* Wt = WtA + (size_t)g * HID * FEAT;
  unsigned short* C = C3 + (size_t)g * M * HID;
  int tid = threadIdx.x;
  int wave = tid >> 6, lane = tid & 63;
  int quad = lane >> 4, r = lane & 15;
  int m0 = bx * 128 + wave * 32;
  int ra0 = m0 + r;      if (ra0 >= M) ra0 = 0;
  int ra1 = m0 + 16 + r; if (ra1 >= M) ra1 = 0;
  const unsigned short* pa0 = A + (size_t)ra0 * FEAT + quad * 8;
  const unsigned short* pa1 = A + (size_t)ra1 * FEAT + quad * 8;
  f32x4 acc[2][8];
#pragma unroll
  for (int i = 0; i < 2; i++)
#pragma unroll
    for (int j = 0; j < 8; j++) acc[i][j] = (f32x4){0.f, 0.f, 0.f, 0.f};
  for (int k0 = 0; k0 < FEAT; k0 += 32) {
    bf16x8 a0 = *(const bf16x8*)(pa0 + k0);
    bf16x8 a1 = *(const bf16x8*)(pa1 + k0);
#pragma unroll
    for (int nt = 0; nt < 8; nt++) {
      bf16x8 b = *(const bf16x8*)(Wt + (size_t)(nt * 16 + r) * FEAT + k0 + quad * 8);
      acc[0][nt] = __builtin_amdgcn_mfma_f32_16x16x32_bf16(a0, b, acc[0][nt], 0, 0, 0);
      acc[1][nt] = __builtin_amdgcn_mfma_f32_16x16x32_bf16(a1, b, acc[1][nt], 0, 0, 0);
    }
  }
#pragma unroll
  for (int t = 0; t < 2; t++)
#pragma unroll
    for (int reg = 0; reg < 4; reg++) {
      int row = m0 + t * 16 + quad * 4 + reg;
      if (row < M) {
#pragma unroll
        for (int nt = 0; nt < 8; nt++)
          C[(size_t)row * HID + nt * 16 + r] = f2bf(acc[t][nt][reg]);
      }
    }
}

__global__ __launch_bounds__(256) void k_gemm2_b(const unsigned short* __restrict__ A3,
                                                 const unsigned short* __restrict__ WtA,
                                                 unsigned short* __restrict__ C3, int M) {
  int g = blockIdx.y;
  const unsigned short* A = A3 + (size_t)g * M * HID;
  const unsigned short* Wt = WtA + (size_t)g * NCLS * HID;
  unsigned short* C = C3 + (size_t)g * M * NCLS;
  int tid = threadIdx.x;
  int wave = tid >> 6, lane = tid & 63;
  int quad = lane >> 4, r = lane & 15;
  int m0 = blockIdx.x * 128 + wave * 32;
  int ra0 = m0 + r;      if (ra0 >= M) ra0 = 0;
  int ra1 = m0 + 16 + r; if (ra1 >= M) ra1 = 0;
  const unsigned short* pa0 = A + (size_t)ra0 * HID + quad * 8;
  const unsigned short* pa1 = A + (size_t)ra1 * HID + quad * 8;
  f32x4 acc[2][4];
#pragma unroll
  for (int i = 0; i < 2; i++)
#pragma unroll
    for (int j = 0; j < 4; j++) acc[i][j] = (f32x4){0.f, 0.f, 0.f, 0.f};
  for (int k0 = 0; k0 < HID; k0 += 32) {
    bf16x8 a0 = *(const bf16x8*)(pa0 + k0);
    bf16x8 a1 = *(const bf16x8*)(pa1 + k0);
#pragma unroll
    for (int nt = 0; nt < 4; nt++) {
      bf16x8 b = *(const bf16x8*)(Wt + (size_t)(nt * 16 + r) * HID + k0 + quad * 8);
      acc[0][nt] = __builtin_amdgcn_mfma_f32_16x16x32_bf16(a0, b, acc[0][nt], 0, 0, 0);
      acc[1][nt] = __builtin_amdgcn_mfma_f32_16x16x32_bf16(a1, b, acc[1][nt], 0, 0, 0);
    }
  }
#pragma unroll
  for (int t = 0; t < 2; t++)
#pragma unroll
    for (int reg = 0; reg < 4; reg++) {
      int row = m0 + t * 16 + quad * 4 + reg;
      if (row < M) {
#pragma unroll
        for (int nt = 0; nt < 4; nt++)
          C[(size_t)row * NCLS + nt * 16 + r] = f2bf(acc[t][nt][reg]);
      }
    }
}

// ---------------- SpMM (HID=128), batched over g (round-2 proven form) ----------
__global__ __launch_bounds__(256) void k_spmm128_b(const int* __restrict__ rp_all,
                                                   const int2* __restrict__ edges,
                                                   const unsigned short* __restrict__ dense3,
                                                   unsigned short* __restrict__ out3, int n) {
  int g = blockIdx.y;
  const int* rp = rp_all + (size_t)g * (NNODES + 1);
  const unsigned short* dense = dense3 + (size_t)g * NNODES * HID;
  unsigned short* out = out3 + (size_t)g * NNODES * HID;
  int w = (blockIdx.x * blockDim.x + threadIdx.x) >> 6;
  int lane = threadIdx.x & 63;
  if (w >= n) return;
  int grp = lane >> 4;    // 0..3
  int sub = lane & 15;    // feats sub*8 .. sub*8+7
  int s = rp[w], e = rp[w + 1];
  f32x2 a0[4], a1[4];
#pragma unroll
  for (int q = 0; q < 4; q++) { a0[q] = (f32x2){0.f, 0.f}; a1[q] = (f32x2){0.f, 0.f}; }
  for (int j = s; j < e; j += 8) {
    int e0 = j + grp, e1 = j + 4 + grp;
    bool k0 = e0 < e, k1 = e1 < e;
    int2 d0 = edges[k0 ? e0 : s];
    int2 d1 = edges[k1 ? e1 : s];
    uint4 u0 = *(const uint4*)(dense + (size_t)d0.x * HID + sub * 8);
    uint4 u1 = *(const uint4*)(dense + (size_t)d1.x * HID + sub * 8);
    float f0 = k0 ? __int_as_float(d0.y) : 0.f;
    float f1 = k1 ? __int_as_float(d1.y) : 0.f;
    f32x2 v0; v0.x = f0; v0.y = f0;
    f32x2 v1; v1.x = f1; v1.y = f1;
    fma8(u0, v0, a0);
    fma8(u1, v1, a1);
  }
  unsigned int pk[4];
#pragma unroll
  for (int q = 0; q < 4; q++) {
    float lo = a0[q].x + a1[q].x;
    float hi = a0[q].y + a1[q].y;
    lo += __shfl_xor(lo, 32, 64); lo += __shfl_xor(lo, 16, 64);
    hi += __shfl_xor(hi, 32, 64); hi += __shfl_xor(hi, 16, 64);
    lo = fmaxf(lo, 0.f); hi = fmaxf(hi, 0.f);
    pk[q] = (unsigned int)f2bf(lo) | ((unsigned int)f2bf(hi) << 16);
  }
  if (lane < 16) {
    uint4 o; o.x = pk[0]; o.y = pk[1]; o.z = pk[2]; o.w = pk[3];
    *(uint4*)(out + (size_t)w * HID + sub * 8) = o;
  }
}

// ------- fused final SpMM (NCLS=64): 3 graphs INTERLEAVED + bias/gate + log_softmax
// Per chunk-iteration the wave issues 3 independent gathers (one per graph) ->
// 3x memory-level parallelism vs the sequential per-graph loop. Scale-combine
// happens before the shuffle tree (1x reduce instead of 3x).
__global__ __launch_bounds__(256) void k_spmm64_final(const int* __restrict__ rp_all,
                                                      const int2* __restrict__ edges,
                                                      const unsigned short* __restrict__ dense3,
                                                      const float* __restrict__ b0p,
                                                      const float* __restrict__ b1p,
                                                      const float* __restrict__ b2p,
                                                      const float* __restrict__ gate,
                                                      float* __restrict__ outp, int n) {
  int w = (blockIdx.x * blockDim.x + threadIdx.x) >> 6;
  int lane = threadIdx.x & 63;
  if (w >= n) return;
  int grp = lane >> 3;    // 0..7: edge slot
  int sub = lane & 7;     // classes sub*8 .. sub*8+7
  int s[3], e[3];
#pragma unroll
  for (int g = 0; g < 3; g++) {
    s[g] = __builtin_amdgcn_readfirstlane(rp_all[(size_t)g * (NNODES + 1) + w]);
    e[g] = __builtin_amdgcn_readfirstlane(rp_all[(size_t)g * (NNODES + 1) + w + 1]);
  }
  int nit = 0;
#pragma unroll
  for (int g = 0; g < 3; g++) {
    int t = (e[g] - s[g] + 7) >> 3;
    nit = (t > nit) ? t : nit;
  }
  f32x2 ac0[4], ac1[4], ac2[4];
#pragma unroll
  for (int q = 0; q < 4; q++) {
    ac0[q] = (f32x2){0.f, 0.f}; ac1[q] = (f32x2){0.f, 0.f}; ac2[q] = (f32x2){0.f, 0.f};
  }
  const unsigned short* d0b = dense3;
  const unsigned short* d1b = dense3 + (size_t)NNODES * NCLS;
  const unsigned short* d2b = dense3 + (size_t)2 * NNODES * NCLS;
  for (int it = 0; it < nit; it++) {
    int j0 = s[0] + it * 8 + grp, j1 = s[1] + it * 8 + grp, j2 = s[2] + it * 8 + grp;
    bool k0 = j0 < e[0], k1 = j1 < e[1], k2 = j2 < e[2];
    int2 d0 = edges[k0 ? j0 : s[0]];
    int2 d1 = edges[k1 ? j1 : s[1]];
    int2 d2 = edges[k2 ? j2 : s[2]];
    uint4 u0 = *(const uint4*)(d0b + (size_t)d0.x * NCLS + sub * 8);
    uint4 u1 = *(const uint4*)(d1b + (size_t)d1.x * NCLS + sub * 8);
    uint4 u2 = *(const uint4*)(d2b + (size_t)d2.x * NCLS + sub * 8);
    float f0 = k0 ? __int_as_float(d0.y) : 0.f;
    float f1 = k1 ? __int_as_float(d1.y) : 0.f;
    float f2 = k2 ? __int_as_float(d2.y) : 0.f;
    f32x2 v0; v0.x = f0; v0.y = f0;
    f32x2 v1; v1.x = f1; v1.y = f1;
    f32x2 v2; v2.x = f2; v2.y = f2;
    fma8(u0, v0, ac0);
    fma8(u1, v1, ac1);
    fma8(u2, v2, ac2);
  }
  float gv = gate[0];
  float omg = 1.0f - gv;
  // bias seed: gv*b0 + (1-gv)*(b1+b2)
  float tot[8];
  {
    float4 x0 = *(const float4*)(b0p + sub * 8), x1 = *(const float4*)(b0p + sub * 8 + 4);
    float4 y0 = *(const float4*)(b1p + sub * 8), y1 = *(const float4*)(b1p + sub * 8 + 4);
    float4 z0 = *(const float4*)(b2p + sub * 8), z1 = *(const float4*)(b2p + sub * 8 + 4);
    tot[0] = gv * x0.x + omg * (y0.x + z0.x); tot[1] = gv * x0.y + omg * (y0.y + z0.y);
    tot[2] = gv * x0.z + omg * (y0.z + z0.z); tot[3] = gv * x0.w + omg * (y0.w + z0.w);
    tot[4] = gv * x1.x + omg * (y1.x + z1.x); tot[5] = gv * x1.y + omg * (y1.y + z1.y);
    tot[6] = gv * x1.z + omg * (y1.z + z1.z); tot[7] = gv * x1.w + omg * (y1.w + z1.w);
  }
  // scale-combine BEFORE the shuffle tree: one reduce for all 3 graphs
#pragma unroll
  for (int q = 0; q < 4; q++) {
    float lo = gv * ac0[q].x + omg * (ac1[q].x + ac2[q].x);
    float hi = gv * ac0[q].y + omg * (ac1[q].y + ac2[q].y);
    lo += __shfl_xor(lo, 32, 64); lo += __shfl_xor(lo, 16, 64); lo += __shfl_xor(lo, 8, 64);
    hi += __shfl_xor(hi, 32, 64); hi += __shfl_xor(hi, 16, 64); hi += __shfl_xor(hi, 8, 64);
    tot[2 * q] += lo;
    tot[2 * q + 1] += hi;
  }
  // fused log_softmax over 64 classes (8 local + shfl across sub bits 0-2)
  float m = tot[0];
#pragma unroll
  for (int i = 1; i < 8; i++) m = fmaxf(m, tot[i]);
  m = fmaxf(m, __shfl_xor(m, 1, 64));
  m = fmaxf(m, __shfl_xor(m, 2, 64));
  m = fmaxf(m, __shfl_xor(m, 4, 64));
  float sum = 0.f;
#pragma unroll
  for (int i = 0; i < 8; i++) sum += expf(tot[i] - m);
  sum += __shfl_xor(sum, 1, 64);
  sum += __shfl_xor(sum, 2, 64);
  sum += __shfl_xor(sum, 4, 64);
  float ls = m + logf(sum);
  if (grp == 0) {
    size_t o = (size_t)w * NCLS + sub * 8;
    *(float4*)(outp + o)     = make_float4(tot[0] - ls, tot[1] - ls, tot[2] - ls, tot[3] - ls);
    *(float4*)(outp + o + 4) = make_float4(tot[4] - ls, tot[5] - ls, tot[6] - ls, tot[7] - ls);
  }
}

extern "C" void kernel_launch(void* const* d_in, const int* in_sizes, int n_in,
                              void* d_out, int out_size, void* d_ws, size_t ws_size,
                              hipStream_t stream) {
  (void)in_sizes; (void)n_in; (void)out_size; (void)ws_size;
  const float* x = (const float*)d_in[0];
  const int*   rows[3]   = {(const int*)d_in[1], (const int*)d_in[4], (const int*)d_in[7]};
  const int*   colsIn[3] = {(const int*)d_in[2], (const int*)d_in[5], (const int*)d_in[8]};
  const float* valsIn[3] = {(const float*)d_in[3], (const float*)d_in[6], (const float*)d_in[9]};
  const float* Whid[3] = {(const float*)d_in[10], (const float*)d_in[13], (const float*)d_in[16]};
  const float* Wout[3] = {(const float*)d_in[11], (const float*)d_in[14], (const float*)d_in[17]};
  const float* bout[3] = {(const float*)d_in[12], (const float*)d_in[15], (const float*)d_in[18]};
  const float* gate = (const float*)d_in[19];
  float* out = (float*)d_out;

  const int N = NNODES, E = NEDGES;
  size_t off = 0;
  auto ws = [&](size_t bytes) {
    void* p = (char*)d_ws + off;
    off += (bytes + 255) & ~(size_t)255;
    return p;
  };
  // Region R1 (76.8 MB): x_bf early; h1[3] later (aliased; x_bf dead after gemm1).
  unsigned short* R1 = (unsigned short*)ws((size_t)3 * N * HID * 2);
  unsigned short* x_bf = R1;
  unsigned short* h13  = R1;
  // hsup3: gemm1 output; later reused as gemm2 output (h2) per g.
  unsigned short* hsup3 = (unsigned short*)ws((size_t)3 * N * HID * 2);
  unsigned short* Wt1a = (unsigned short*)ws((size_t)3 * HID * FEAT * 2);
  unsigned short* Wt2a = (unsigned short*)ws((size_t)3 * NCLS * HID * 2);
  int2* edges   = (int2*)ws(((size_t)3 * E + 64) * 8);   // +64 slack for clamped tail reads
  int*  rp_all  = (int*) ws((size_t)3 * (N + 1) * 4);
  int*  bhist   = (int*) ws(NB3 * 4);
  int*  boff    = (int*) ws((NB3 + 1) * 4);
  int*  gcur    = (int*) ws(NB3 * 4);

  dim3 b256(256);
  dim3 gRows3((N + 3) / 4, 3);
  int nbGemm = (N + 127) / 128;

  k_convert_bf16<<<(N * FEAT / 4 + 255) / 256, b256, 0, stream>>>(x, x_bf, N * FEAT / 4);
  k_transpose3<<<dim3((FEAT * HID + 255) / 256, 3), b256, 0, stream>>>(
      Whid[0], Whid[1], Whid[2], Wt1a, Wt1a + (size_t)HID * FEAT, Wt1a + (size_t)2 * HID * FEAT,
      FEAT, HID);
  k_transpose3<<<dim3((HID * NCLS + 255) / 256, 3), b256, 0, stream>>>(
      Wout[0], Wout[1], Wout[2], Wt2a, Wt2a + (size_t)NCLS * HID, Wt2a + (size_t)2 * NCLS * HID,
      HID, NCLS);

  // CSR build (round-2 proven): hist -> scan -> compact scatter -> in-bucket sort
  hipMemsetAsync(bhist, 0, NB3 * 4, stream);
  k_bhist<<<dim3((E + 4095) / 4096, 3), b256, 0, stream>>>(rows[0], rows[1], rows[2], bhist);
  k_bscan<<<1, 1024, 0, stream>>>(bhist, boff);
  hipMemcpyAsync(gcur, boff, NB3 * 4, hipMemcpyDeviceToDevice, stream);
  k_bucket_scatter<<<dim3((E + SC_CHUNK - 1) / SC_CHUNK, 3), dim3(SC_THREADS), 0, stream>>>(
      rows[0], rows[1], rows[2], colsIn[0], colsIn[1], colsIn[2],
      valsIn[0], valsIn[1], valsIn[2], gcur, edges);
  k_bucket_sort<<<dim3(NBG, 3), 512, 0, stream>>>(boff, edges, rp_all);

  k_gemm1_b<<<dim3(3 * nbGemm), b256, 0, stream>>>(x_bf, Wt1a, hsup3, N);
  k_spmm128_b<<<gRows3, b256, 0, stream>>>(rp_all, edges, hsup3, h13, N);
  k_gemm2_b<<<dim3(nbGemm, 3), b256, 0, stream>>>(h13, Wt2a, hsup3, N);
  k_spmm64_final<<<dim3((N + 3) / 4), b256, 0, stream>>>(
      rp_all, edges, hsup3, bout[0], bout[1], bout[2], gate, out, N);
}

// Round 8
// 690.355 us; speedup vs baseline: 1.2396x; 1.0104x over previous
//
#include <hip/hip_runtime.h>
#include <math.h>

#define NNODES 100000
#define NEDGES 1600000
#define FEAT 256
#define HID 128
#define NCLS 64
#define RPB 512                 // rows per bucket
#define NBG 196                 // buckets per graph = ceil(100000/512)
#define NB3 (3 * NBG)           // 588
#define CAP 8832                // per-bucket edge capacity (mean 8163 + 7 sigma)
#define SC_CHUNK 8192           // edges per scatter block (LDS-staged)
#define SC_THREADS 1024         // 16 waves/block

typedef __attribute__((ext_vector_type(8))) short bf16x8;
typedef __attribute__((ext_vector_type(4))) float f32x4;
typedef __attribute__((ext_vector_type(2))) float f32x2;

__device__ __forceinline__ unsigned short f2bf(float f) {
  union { float f; unsigned int i; } c; c.f = f;
  unsigned int u = c.i;
  return (unsigned short)((u + 0x7fffu + ((u >> 16) & 1u)) >> 16);  // RNE
}

// 8 bf16 (as uint4) * scalar-pair vv -> 4 packed f32x2 accumulators
__device__ __forceinline__ void fma8(const uint4 u, const f32x2 vv, f32x2* a) {
  f32x2 p0, p1, p2, p3;
  p0.x = __uint_as_float(u.x << 16); p0.y = __uint_as_float(u.x & 0xffff0000u);
  p1.x = __uint_as_float(u.y << 16); p1.y = __uint_as_float(u.y & 0xffff0000u);
  p2.x = __uint_as_float(u.z << 16); p2.y = __uint_as_float(u.z & 0xffff0000u);
  p3.x = __uint_as_float(u.w << 16); p3.y = __uint_as_float(u.w & 0xffff0000u);
  a[0] += p0 * vv; a[1] += p1 * vv; a[2] += p2 * vv; a[3] += p3 * vv;
}

// ---------------- fused prep: x->bf16 | W transposes | bucket histogram --------
// blockIdx.x range-split; all sections 256-thread. Replaces 4 dispatches.
#define NB_CONV 25000                      // N*FEAT/4/256 (exact)
#define NB_T1 128                          // FEAT*HID/256 (exact)
#define NB_T2 32                           // HID*NCLS/256 (exact)
#define NB_BH 391                          // ceil(NEDGES/4096)
#define PREP_BLOCKS (NB_CONV + 3 * NB_T1 + 3 * NB_T2 + 3 * NB_BH)

__global__ __launch_bounds__(256) void k_prep(
    const float* __restrict__ x, unsigned short* __restrict__ x_bf,
    const float* __restrict__ W10, const float* __restrict__ W11, const float* __restrict__ W12,
    unsigned short* __restrict__ Wt1a,
    const float* __restrict__ W20, const float* __restrict__ W21, const float* __restrict__ W22,
    unsigned short* __restrict__ Wt2a,
    const int* __restrict__ r0, const int* __restrict__ r1, const int* __restrict__ r2,
    int* __restrict__ bhist) {
  __shared__ int h[NBG];
  int b = blockIdx.x;
  int tid = threadIdx.x;
  if (b < NB_CONV) {
    int i = b * 256 + tid;
    float4 v = ((const float4*)x)[i];
    ushort4 o;
    o.x = f2bf(v.x); o.y = f2bf(v.y); o.z = f2bf(v.z); o.w = f2bf(v.w);
    ((ushort4*)x_bf)[i] = o;
    return;
  }
  b -= NB_CONV;
  if (b < 3 * NB_T1) {
    int g = b / NB_T1, bx = b % NB_T1;
    const float* src = (g == 0) ? W10 : (g == 1 ? W11 : W12);
    unsigned short* dst = Wt1a + (size_t)g * HID * FEAT;
    int idx = bx * 256 + tid;           // K=FEAT rows, N=HID cols
    int k = idx / HID, n = idx % HID;
    dst[(size_t)n * FEAT + k] = f2bf(src[idx]);
    return;
  }
  b -= 3 * NB_T1;
  if (b < 3 * NB_T2) {
    int g = b / NB_T2, bx = b % NB_T2;
    const float* src = (g == 0) ? W20 : (g == 1 ? W21 : W22);
    unsigned short* dst = Wt2a + (size_t)g * NCLS * HID;
    int idx = bx * 256 + tid;           // K=HID rows, N=NCLS cols
    int k = idx / NCLS, n = idx % NCLS;
    dst[(size_t)n * HID + k] = f2bf(src[idx]);
    return;
  }
  b -= 3 * NB_T2;
  {
    int g = b / NB_BH, bx = b % NB_BH;
    const int* rr = (g == 0) ? r0 : (g == 1 ? r1 : r2);
    for (int i = tid; i < NBG; i += 256) h[i] = 0;
    __syncthreads();
    int base = bx * 4096;
#pragma unroll
    for (int k = 0; k < 16; k++) {
      int e = base + k * 256 + tid;
      if (e < NEDGES) atomicAdd(&h[rr[e] >> 9], 1);
    }
    __syncthreads();
    for (int i = tid; i < NBG; i += 256)
      if (h[i]) atomicAdd(&bhist[g * NBG + i], h[i]);
  }
}

// single-block exclusive scan over NB3 bucket counts -> boff[0..NB3] and gcur
__global__ __launch_bounds__(1024) void k_bscan(const int* __restrict__ bhist,
                                                int* __restrict__ boff,
                                                int* __restrict__ gcur) {
  __shared__ int sd[2][1024];
  int tid = threadIdx.x;
  int v = (tid < NB3) ? bhist[tid] : 0;
  sd[0][tid] = v;
  __syncthreads();
  int cur = 0;
  for (int off = 1; off < 1024; off <<= 1) {
    int nv = sd[cur][tid];
    if (tid >= off) nv += sd[cur][tid - off];
    sd[cur ^ 1][tid] = nv;
    __syncthreads();
    cur ^= 1;
  }
  int incl = sd[cur][tid];
  if (tid < NB3) { boff[tid] = incl - v; gcur[tid] = incl - v; }
  if (tid == NB3 - 1) boff[NB3] = incl;
}

// ---------------- pass A: coarse bucket scatter (LDS-staged, coalesced writes) ---
__global__ __launch_bounds__(SC_THREADS) void k_bucket_scatter(
    const int* __restrict__ r0, const int* __restrict__ r1, const int* __restrict__ r2,
    const int* __restrict__ c0, const int* __restrict__ c1, const int* __restrict__ c2,
    const float* __restrict__ v0, const float* __restrict__ v1, const float* __restrict__ v2,
    int* __restrict__ gcur, int2* __restrict__ edges) {
  __shared__ int2 stage[SC_CHUNK];            // 64 KB
  __shared__ unsigned char bid[SC_CHUNK];     // 8 KB  (NBG=196 < 256)
  __shared__ int hist[NBG];
  __shared__ int lbase[NBG];
  __shared__ int gstart[NBG];
  __shared__ int cur[NBG];
  __shared__ int sd[2][256];
  int g = blockIdx.y;
  const int*   rr = (g == 0) ? r0 : (g == 1 ? r1 : r2);
  const int*   cc = (g == 0) ? c0 : (g == 1 ? c1 : c2);
  const float* vv = (g == 0) ? v0 : (g == 1 ? v1 : v2);
  int tid = threadIdx.x;
  int base = blockIdx.x * SC_CHUNK;
  int cnt_blk = NEDGES - base;
  if (cnt_blk > SC_CHUNK) cnt_blk = SC_CHUNK;

  for (int i = tid; i < NBG; i += SC_THREADS) hist[i] = 0;
  __syncthreads();

  int rowv[SC_CHUNK / SC_THREADS];
  int colv[SC_CHUNK / SC_THREADS];
  float valv[SC_CHUNK / SC_THREADS];
#pragma unroll
  for (int k = 0; k < SC_CHUNK / SC_THREADS; k++) {
    int e = base + k * SC_THREADS + tid;
    bool ok = e < NEDGES;
    rowv[k] = ok ? rr[e] : -1;
    colv[k] = ok ? cc[e] : 0;
    valv[k] = ok ? vv[e] : 0.f;
    if (ok) atomicAdd(&hist[rowv[k] >> 9], 1);
  }
  __syncthreads();

  if (tid < 256) sd[0][tid] = (tid < NBG) ? hist[tid] : 0;
  __syncthreads();
  int c = 0;
  for (int off = 1; off < 256; off <<= 1) {
    if (tid < 256) {
      int nv = sd[c][tid];
      if (tid >= off) nv += sd[c][tid - off];
      sd[c ^ 1][tid] = nv;
    }
    __syncthreads();
    c ^= 1;
  }
  if (tid < NBG) {
    int cn = hist[tid];
    int excl = sd[c][tid] - cn;
    lbase[tid] = excl;
    cur[tid] = excl;
    gstart[tid] = cn ? atomicAdd(&gcur[g * NBG + tid], cn) : 0;
  }
  __syncthreads();

#pragma unroll
  for (int k = 0; k < SC_CHUNK / SC_THREADS; k++) {
    if (rowv[k] >= 0) {
      int b = rowv[k] >> 9;
      int p = atomicAdd(&cur[b], 1);
      stage[p] = make_int2(((rowv[k] & (RPB - 1)) << 17) | colv[k], __float_as_int(valv[k]));
      bid[p] = (unsigned char)b;
    }
  }
  __syncthreads();

  for (int i = tid; i < cnt_blk; i += SC_THREADS) {
    int b = bid[i];
    int dst = gstart[b] + (i - lbase[b]);
    edges[dst] = stage[i];
  }
}

// ---------------- pass B: in-bucket counting sort (LDS scatter, coalesced IO) ---
__global__ __launch_bounds__(512) void k_bucket_sort(const int* __restrict__ boff,
                                                     int2* __restrict__ edges,
                                                     int* __restrict__ row_ptr_all) {
  __shared__ int2 stage[CAP];   // 70.7 KB
  __shared__ int hist[RPB];
  __shared__ int sd[2][RPB];
  __shared__ int cur[RPB];
  int g = blockIdx.y, b = blockIdx.x;
  int tid = threadIdx.x;
  int idx = g * NBG + b;
  int base = boff[idx];
  int count = boff[idx + 1] - base;
  if (count > CAP) count = CAP;
  hist[tid] = 0;
  __syncthreads();

  const int KSL = (CAP + 511) / 512;   // 18 slots/thread
  int2 ev[KSL];
#pragma unroll
  for (int k = 0; k < KSL; k++) {
    int i = tid + k * 512;
    if (i < count) {
      ev[k] = edges[base + i];
      atomicAdd(&hist[ev[k].x >> 17], 1);
    }
  }
  __syncthreads();

  int v = hist[tid];
  sd[0][tid] = v;
  __syncthreads();
  int c2 = 0;
  for (int off = 1; off < 512; off <<= 1) {
    int nv = sd[c2][tid];
    if (tid >= off) nv += sd[c2][tid - off];
    sd[c2 ^ 1][tid] = nv;
    __syncthreads();
    c2 ^= 1;
  }
  int excl = sd[c2][tid] - v;
  int row = b * RPB + tid;
  if (row <= NNODES) row_ptr_all[g * (NNODES + 1) + row] = base + excl;
  cur[tid] = excl;
  __syncthreads();

#pragma unroll
  for (int k = 0; k < KSL; k++) {
    int i = tid + k * 512;
    if (i < count) {
      int lr = ev[k].x >> 17;
      int p = atomicAdd(&cur[lr], 1);
      stage[p] = make_int2(ev[k].x & 0x1FFFF, ev[k].y);  // strip row bits: col only
    }
  }
  __syncthreads();

  for (int i = tid; i < count; i += 512) edges[base + i] = stage[i];
}

// ---------------- batched bf16 MFMA GEMMs ----------------
__global__ __launch_bounds__(256) void k_gemm1_b(const unsigned short* __restrict__ A,
                                                 const unsigned short* __restrict__ WtA,
                                                 unsigned short* __restrict__ C3, int M) {
  int bxy = blockIdx.x;
  int g = bxy % 3;
  int bx = bxy / 3;
  const unsigned short* Wt = WtA + (size_t)g * HID * FEAT;
  unsigned short* C = C3 + (size_t)g * M * HID;
  int tid = threadIdx.x;
  int wave = tid >> 6, lane = tid & 63;
  int quad = lane >> 4, r = lane & 15;
  int m0 = bx * 128 + wave * 32;
  int ra0 = m0 + r;      if (ra0 >= M) ra0 = 0;
  int ra1 = m0 + 16 + r; if (ra1 >= M) ra1 = 0;
  const unsigned short* pa0 = A + (size_t)ra0 * FEAT + quad * 8;
  const unsigned short* pa1 = A + (size_t)ra1 * FEAT + quad * 8;
  f32x4 acc[2][8];
#pragma unroll
  for (int i = 0; i < 2; i++)
#pragma unroll
    for (int j = 0; j < 8; j++) acc[i][j] = (f32x4){0.f, 0.f, 0.f, 0.f};
  for (int k0 = 0; k0 < FEAT; k0 += 32) {
    bf16x8 a0 = *(const bf16x8*)(pa0 + k0);
    bf16x8 a1 = *(const bf16x8*)(pa1 + k0);
#pragma unroll
    for (int nt = 0; nt < 8; nt++) {
      bf16x8 b = *(const bf16x8*)(Wt + (size_t)(nt * 16 + r) * FEAT + k0 + quad * 8);
      acc[0][nt] = __builtin_amdgcn_mfma_f32_16x16x32_bf16(a0, b, acc[0][nt], 0, 0, 0);
      acc[1][nt] = __builtin_amdgcn_mfma_f32_16x16x32_bf16(a1, b, acc[1][nt], 0, 0, 0);
    }
  }
#pragma unroll
  for (int t = 0; t < 2; t++)
#pragma unroll
    for (int reg = 0; reg < 4; reg++) {
      int row = m0 + t * 16 + quad * 4 + reg;
      if (row < M) {
#pragma unroll
        for (int nt = 0; nt < 8; nt++)
          C[(size_t)row * HID + nt * 16 + r] = f2bf(acc[t][nt][reg]);
      }
    }
}

__global__ __launch_bounds__(256) void k_gemm2_b(const unsigned short* __restrict__ A3,
                                                 const unsigned short* __restrict__ WtA,
                                                 unsigned short* __restrict__ C3, int M) {
  int g = blockIdx.y;
  const unsigned short* A = A3 + (size_t)g * M * HID;
  const unsigned short* Wt = WtA + (size_t)g * NCLS * HID;
  unsigned short* C = C3 + (size_t)g * M * NCLS;
  int tid = threadIdx.x;
  int wave = tid >> 6, lane = tid & 63;
  int quad = lane >> 4, r = lane & 15;
  int m0 = blockIdx.x * 128 + wave * 32;
  int ra0 = m0 + r;      if (ra0 >= M) ra0 = 0;
  int ra1 = m0 + 16 + r; if (ra1 >= M) ra1 = 0;
  const unsigned short* pa0 = A + (size_t)ra0 * HID + quad * 8;
  const unsigned short* pa1 = A + (size_t)ra1 * HID + quad * 8;
  f32x4 acc[2][4];
#pragma unroll
  for (int i = 0; i < 2; i++)
#pragma unroll
    for (int j = 0; j < 4; j++) acc[i][j] = (f32x4){0.f, 0.f, 0.f, 0.f};
  for (int k0 = 0; k0 < HID; k0 += 32) {
    bf16x8 a0 = *(const bf16x8*)(pa0 + k0);
    bf16x8 a1 = *(const bf16x8*)(pa1 + k0);
#pragma unroll
    for (int nt = 0; nt < 4; nt++) {
      bf16x8 b = *(const bf16x8*)(Wt + (size_t)(nt * 16 + r) * HID + k0 + quad * 8);
      acc[0][nt] = __builtin_amdgcn_mfma_f32_16x16x32_bf16(a0, b, acc[0][nt], 0, 0, 0);
      acc[1][nt] = __builtin_amdgcn_mfma_f32_16x16x32_bf16(a1, b, acc[1][nt], 0, 0, 0);
    }
  }
#pragma unroll
  for (int t = 0; t < 2; t++)
#pragma unroll
    for (int reg = 0; reg < 4; reg++) {
      int row = m0 + t * 16 + quad * 4 + reg;
      if (row < M) {
#pragma unroll
        for (int nt = 0; nt < 4; nt++)
          C[(size_t)row * NCLS + nt * 16 + r] = f2bf(acc[t][nt][reg]);
      }
    }
}

// ---------------- SpMM (HID=128), batched over g (round-2 proven form) ----------
__global__ __launch_bounds__(256) void k_spmm128_b(const int* __restrict__ rp_all,
                                                   const int2* __restrict__ edges,
                                                   const unsigned short* __restrict__ dense3,
                                                   unsigned short* __restrict__ out3, int n) {
  int g = blockIdx.y;
  const int* rp = rp_all + (size_t)g * (NNODES + 1);
  const unsigned short* dense = dense3 + (size_t)g * NNODES * HID;
  unsigned short* out = out3 + (size_t)g * NNODES * HID;
  int w = (blockIdx.x * blockDim.x + threadIdx.x) >> 6;
  int lane = threadIdx.x & 63;
  if (w >= n) return;
  int grp = lane >> 4;    // 0..3
  int sub = lane & 15;    // feats sub*8 .. sub*8+7
  int s = rp[w], e = rp[w + 1];
  f32x2 a0[4], a1[4];
#pragma unroll
  for (int q = 0; q < 4; q++) { a0[q] = (f32x2){0.f, 0.f}; a1[q] = (f32x2){0.f, 0.f}; }
  for (int j = s; j < e; j += 8) {
    int e0 = j + grp, e1 = j + 4 + grp;
    bool k0 = e0 < e, k1 = e1 < e;
    int2 d0 = edges[k0 ? e0 : s];
    int2 d1 = edges[k1 ? e1 : s];
    uint4 u0 = *(const uint4*)(dense + (size_t)d0.x * HID + sub * 8);
    uint4 u1 = *(const uint4*)(dense + (size_t)d1.x * HID + sub * 8);
    float f0 = k0 ? __int_as_float(d0.y) : 0.f;
    float f1 = k1 ? __int_as_float(d1.y) : 0.f;
    f32x2 v0; v0.x = f0; v0.y = f0;
    f32x2 v1; v1.x = f1; v1.y = f1;
    fma8(u0, v0, a0);
    fma8(u1, v1, a1);
  }
  unsigned int pk[4];
#pragma unroll
  for (int q = 0; q < 4; q++) {
    float lo = a0[q].x + a1[q].x;
    float hi = a0[q].y + a1[q].y;
    lo += __shfl_xor(lo, 32, 64); lo += __shfl_xor(lo, 16, 64);
    hi += __shfl_xor(hi, 32, 64); hi += __shfl_xor(hi, 16, 64);
    lo = fmaxf(lo, 0.f); hi = fmaxf(hi, 0.f);
    pk[q] = (unsigned int)f2bf(lo) | ((unsigned int)f2bf(hi) << 16);
  }
  if (lane < 16) {
    uint4 o; o.x = pk[0]; o.y = pk[1]; o.z = pk[2]; o.w = pk[3];
    *(uint4*)(out + (size_t)w * HID + sub * 8) = o;
  }
}

// ------- fused final SpMM (NCLS=64): 3 graphs interleaved, edge-prefetch pipeline
__global__ __launch_bounds__(256) void k_spmm64_final(const int* __restrict__ rp_all,
                                                      const int2* __restrict__ edges,
                                                      const unsigned short* __restrict__ dense3,
                                                      const float* __restrict__ b0p,
                                                      const float* __restrict__ b1p,
                                                      const float* __restrict__ b2p,
                                                      const float* __restrict__ gate,
                                                      float* __restrict__ outp, int n) {
  int w = (blockIdx.x * blockDim.x + threadIdx.x) >> 6;
  int lane = threadIdx.x & 63;
  if (w >= n) return;
  int grp = lane >> 3;    // 0..7: edge slot
  int sub = lane & 7;     // classes sub*8 .. sub*8+7
  int s[3], e[3];
#pragma unroll
  for (int g = 0; g < 3; g++) {
    s[g] = __builtin_amdgcn_readfirstlane(rp_all[(size_t)g * (NNODES + 1) + w]);
    e[g] = __builtin_amdgcn_readfirstlane(rp_all[(size_t)g * (NNODES + 1) + w + 1]);
  }
  int nit = 0;
#pragma unroll
  for (int g = 0; g < 3; g++) {
    int t = (e[g] - s[g] + 7) >> 3;
    nit = (t > nit) ? t : nit;
  }
  f32x2 ac0[4], ac1[4], ac2[4];
#pragma unroll
  for (int q = 0; q < 4; q++) {
    ac0[q] = (f32x2){0.f, 0.f}; ac1[q] = (f32x2){0.f, 0.f}; ac2[q] = (f32x2){0.f, 0.f};
  }
  const unsigned short* d0b = dense3;
  const unsigned short* d1b = dense3 + (size_t)NNODES * NCLS;
  const unsigned short* d2b = dense3 + (size_t)2 * NNODES * NCLS;
  // prologue: load iteration-0 edge records
  int j0 = s[0] + grp, j1 = s[1] + grp, j2 = s[2] + grp;
  bool k0 = j0 < e[0], k1 = j1 < e[1], k2 = j2 < e[2];
  int2 d0 = edges[k0 ? j0 : s[0]];
  int2 d1 = edges[k1 ? j1 : s[1]];
  int2 d2 = edges[k2 ? j2 : s[2]];
  for (int it = 0; it < nit; it++) {
    // issue gathers for current edges
    uint4 u0 = *(const uint4*)(d0b + (size_t)d0.x * NCLS + sub * 8);
    uint4 u1 = *(const uint4*)(d1b + (size_t)d1.x * NCLS + sub * 8);
    uint4 u2 = *(const uint4*)(d2b + (size_t)d2.x * NCLS + sub * 8);
    // prefetch next iteration's edge records (hides edge-load leg under gathers)
    int m0i = s[0] + (it + 1) * 8 + grp, m1i = s[1] + (it + 1) * 8 + grp,
        m2i = s[2] + (it + 1) * 8 + grp;
    bool kn0 = m0i < e[0], kn1 = m1i < e[1], kn2 = m2i < e[2];
    int2 dn0 = edges[kn0 ? m0i : s[0]];
    int2 dn1 = edges[kn1 ? m1i : s[1]];
    int2 dn2 = edges[kn2 ? m2i : s[2]];
    float f0 = k0 ? __int_as_float(d0.y) : 0.f;
    float f1 = k1 ? __int_as_float(d1.y) : 0.f;
    float f2 = k2 ? __int_as_float(d2.y) : 0.f;
    f32x2 v0; v0.x = f0; v0.y = f0;
    f32x2 v1; v1.x = f1; v1.y = f1;
    f32x2 v2; v2.x = f2; v2.y = f2;
    fma8(u0, v0, ac0);
    fma8(u1, v1, ac1);
    fma8(u2, v2, ac2);
    d0 = dn0; d1 = dn1; d2 = dn2;
    k0 = kn0; k1 = kn1; k2 = kn2;
  }
  float gv = gate[0];
  float omg = 1.0f - gv;
  // bias seed: gv*b0 + (1-gv)*(b1+b2)
  float tot[8];
  {
    float4 x0 = *(const float4*)(b0p + sub * 8), x1 = *(const float4*)(b0p + sub * 8 + 4);
    float4 y0 = *(const float4*)(b1p + sub * 8), y1 = *(const float4*)(b1p + sub * 8 + 4);
    float4 z0 = *(const float4*)(b2p + sub * 8), z1 = *(const float4*)(b2p + sub * 8 + 4);
    tot[0] = gv * x0.x + omg * (y0.x + z0.x); tot[1] = gv * x0.y + omg * (y0.y + z0.y);
    tot[2] = gv * x0.z + omg * (y0.z + z0.z); tot[3] = gv * x0.w + omg * (y0.w + z0.w);
    tot[4] = gv * x1.x + omg * (y1.x + z1.x); tot[5] = gv * x1.y + omg * (y1.y + z1.y);
    tot[6] = gv * x1.z + omg * (y1.z + z1.z); tot[7] = gv * x1.w + omg * (y1.w + z1.w);
  }
  // scale-combine BEFORE the shuffle tree: one reduce for all 3 graphs
#pragma unroll
  for (int q = 0; q < 4; q++) {
    float lo = gv * ac0[q].x + omg * (ac1[q].x + ac2[q].x);
    float hi = gv * ac0[q].y + omg * (ac1[q].y + ac2[q].y);
    lo += __shfl_xor(lo, 32, 64); lo += __shfl_xor(lo, 16, 64); lo += __shfl_xor(lo, 8, 64);
    hi += __shfl_xor(hi, 32, 64); hi += __shfl_xor(hi, 16, 64); hi += __shfl_xor(hi, 8, 64);
    tot[2 * q] += lo;
    tot[2 * q + 1] += hi;
  }
  // fused log_softmax over 64 classes (8 local + shfl across sub bits 0-2)
  float m = tot[0];
#pragma unroll
  for (int i = 1; i < 8; i++) m = fmaxf(m, tot[i]);
  m = fmaxf(m, __shfl_xor(m, 1, 64));
  m = fmaxf(m, __shfl_xor(m, 2, 64));
  m = fmaxf(m, __shfl_xor(m, 4, 64));
  float sum = 0.f;
#pragma unroll
  for (int i = 0; i < 8; i++) sum += expf(tot[i] - m);
  sum += __shfl_xor(sum, 1, 64);
  sum += __shfl_xor(sum, 2, 64);
  sum += __shfl_xor(sum, 4, 64);
  float ls = m + logf(sum);
  if (grp == 0) {
    size_t o = (size_t)w * NCLS + sub * 8;
    *(float4*)(outp + o)     = make_float4(tot[0] - ls, tot[1] - ls, tot[2] - ls, tot[3] - ls);
    *(float4*)(outp + o + 4) = make_float4(tot[4] - ls, tot[5] - ls, tot[6] - ls, tot[7] - ls);
  }
}

extern "C" void kernel_launch(void* const* d_in, const int* in_sizes, int n_in,
                              void* d_out, int out_size, void* d_ws, size_t ws_size,
                              hipStream_t stream) {
  (void)in_sizes; (void)n_in; (void)out_size; (void)ws_size;
  const float* x = (const float*)d_in[0];
  const int*   rows[3]   = {(const int*)d_in[1], (const int*)d_in[4], (const int*)d_in[7]};
  const int*   colsIn[3] = {(const int*)d_in[2], (const int*)d_in[5], (const int*)d_in[8]};
  const float* valsIn[3] = {(const float*)d_in[3], (const float*)d_in[6], (const float*)d_in[9]};
  const float* Whid[3] = {(const float*)d_in[10], (const float*)d_in[13], (const float*)d_in[16]};
  const float* Wout[3] = {(const float*)d_in[11], (const float*)d_in[14], (const float*)d_in[17]};
  const float* bout[3] = {(const float*)d_in[12], (const float*)d_in[15], (const float*)d_in[18]};
  const float* gate = (const float*)d_in[19];
  float* out = (float*)d_out;

  const int N = NNODES, E = NEDGES;
  size_t off = 0;
  auto ws = [&](size_t bytes) {
    void* p = (char*)d_ws + off;
    off += (bytes + 255) & ~(size_t)255;
    return p;
  };
  // Region R1 (76.8 MB): x_bf early; h1[3] later (aliased; x_bf dead after gemm1).
  unsigned short* R1 = (unsigned short*)ws((size_t)3 * N * HID * 2);
  unsigned short* x_bf = R1;
  unsigned short* h13  = R1;
  // hsup3: gemm1 output; later reused as gemm2 output (h2) per g.
  unsigned short* hsup3 = (unsigned short*)ws((size_t)3 * N * HID * 2);
  unsigned short* Wt1a = (unsigned short*)ws((size_t)3 * HID * FEAT * 2);
  unsigned short* Wt2a = (unsigned short*)ws((size_t)3 * NCLS * HID * 2);
  int2* edges   = (int2*)ws(((size_t)3 * E + 64) * 8);   // +64 slack for clamped tail reads
  int*  rp_all  = (int*) ws((size_t)3 * (N + 1) * 4);
  int*  bhist   = (int*) ws(NB3 * 4);
  int*  boff    = (int*) ws((NB3 + 1) * 4);
  int*  gcur    = (int*) ws(NB3 * 4);

  dim3 b256(256);
  dim3 gRows3((N + 3) / 4, 3);
  int nbGemm = (N + 127) / 128;

  // fused prep (convert + transposes + bhist) — bhist zeroed first
  hipMemsetAsync(bhist, 0, NB3 * 4, stream);
  k_prep<<<dim3(PREP_BLOCKS), b256, 0, stream>>>(
      x, x_bf, Whid[0], Whid[1], Whid[2], Wt1a,
      Wout[0], Wout[1], Wout[2], Wt2a,
      rows[0], rows[1], rows[2], bhist);
  k_bscan<<<1, 1024, 0, stream>>>(bhist, boff, gcur);
  k_bucket_scatter<<<dim3((E + SC_CHUNK - 1) / SC_CHUNK, 3), dim3(SC_THREADS), 0, stream>>>(
      rows[0], rows[1], rows[2], colsIn[0], colsIn[1], colsIn[2],
      valsIn[0], valsIn[1], valsIn[2], gcur, edges);
  k_bucket_sort<<<dim3(NBG, 3), 512, 0, stream>>>(boff, edges, rp_all);

  k_gemm1_b<<<dim3(3 * nbGemm), b256, 0, stream>>>(x_bf, Wt1a, hsup3, N);
  k_spmm128_b<<<gRows3, b256, 0, stream>>>(rp_all, edges, hsup3, h13, N);
  k_gemm2_b<<<dim3(nbGemm, 3), b256, 0, stream>>>(h13, Wt2a, hsup3, N);
  k_spmm64_final<<<dim3((N + 3) / 4), b256, 0, stream>>>(
      rp_all, edges, hsup3, bout[0], bout[1], bout[2], gate, out, N);
}